// Round 2
// baseline (14127.690 us; speedup 1.0000x reference)
//
#include <hip/hip_runtime.h>
#include <hip/hip_bf16.h>

using bf16 = __hip_bfloat16;

__device__ __forceinline__ float b2f(bf16 v){ return __bfloat162float(v); }
__device__ __forceinline__ bf16 f2b(float v){ return __float2bfloat16(v); }

// dtype-flexible element access: index is in ELEMENTS of type T
template<typename T> __device__ __forceinline__ float ldv(const void* p, long long i);
template<> __device__ __forceinline__ float ldv<float>(const void* p, long long i){ return ((const float*)p)[i]; }
template<> __device__ __forceinline__ float ldv<bf16 >(const void* p, long long i){ return b2f(((const bf16*)p)[i]); }

template<typename T> __device__ __forceinline__ void stv(void* p, long long i, float v);
template<> __device__ __forceinline__ void stv<float>(void* p, long long i, float v){ ((float*)p)[i] = v; }
template<> __device__ __forceinline__ void stv<bf16 >(void* p, long long i, float v){ ((bf16*)p)[i] = f2b(v); }

// ---------------- dtype detection ----------------
__global__ void k_zero_flag(int* f){ *f = 0; }

// If x is float32 data, its low 16-bit halves reinterpreted as bf16 hit
// exp=0xFF (inf/nan) thousands of times in 2M elements. Genuine bf16 N(0,1)
// data never does. flag=1 => inputs are float32.
__global__ void k_detect(const unsigned short* __restrict__ x, long long n, int* __restrict__ flag){
  long long i = blockIdx.x*(long long)blockDim.x + threadIdx.x;
  if (i >= n) return;
  unsigned short u = x[i];
  if ((u & 0x7F80u) == 0x7F80u) atomicOr(flag, 1);
}

// ---------------- prep: mask u8 + masked x (bf16) ----------------
__global__ void k_prep(const void* __restrict__ x, const int* __restrict__ m, const int* __restrict__ flag,
                       bf16* __restrict__ xo, unsigned char* __restrict__ mo, long long n){
  long long i = blockIdx.x*(long long)blockDim.x + threadIdx.x;
  if (i >= n) return;
  int f = *flag;
  int mm = (m[i] != 0);
  mo[i] = (unsigned char)mm;
  float v = f ? ldv<float>(x, i) : ldv<bf16>(x, i);
  xo[i] = f2b(mm ? v : 0.f);
}

// mc[b,y,x] = coarse[b,y/2,x/2] | fine[b,y,x]
__global__ void k_mask_comb(const unsigned char* __restrict__ coarse,
                            const unsigned char* __restrict__ fine,
                            unsigned char* __restrict__ mo,
                            int B, int H, int W){
  long long i = blockIdx.x*(long long)blockDim.x + threadIdx.x;
  long long total = (long long)B*H*W;
  if (i >= total) return;
  int x = (int)(i % W);
  long long t = i / W;
  int y = (int)(t % H);
  int b = (int)(t / H);
  unsigned char c = coarse[((long long)b*(H/2) + (y>>1))*(W/2) + (x>>1)];
  mo[i] = (unsigned char)(c | fine[i]);
}

// ---------------- conv3x3 SAME, masked output ----------------
// in = concat(in0[C0], in1[C1]); inputs always bf16; w dtype TW; out dtype TO
template<typename TW, typename TO>
__device__ __forceinline__ void conv3_body(const bf16* __restrict__ in0, int C0,
    const bf16* __restrict__ in1, int C1, const void* __restrict__ w,
    const unsigned char* __restrict__ mask, void* __restrict__ out, long long out_off,
    int B, int H, int W, int Co){
  long long idx = blockIdx.x*(long long)blockDim.x + threadIdx.x;
  long long total = (long long)B*H*W*Co;
  if (idx >= total) return;
  int co = (int)(idx % Co);
  long long s = idx / Co;
  int x = (int)(s % W);
  long long t = s / W;
  int y = (int)(t % H);
  int b = (int)(t / H);
  if (!mask[s]){ stv<TO>(out, out_off + idx, 0.f); return; }
  const int Ci = C0 + C1;
  float acc = 0.f;
  for (int dy = 0; dy < 3; ++dy){
    int yy = y + dy - 1;
    if ((unsigned)yy >= (unsigned)H) continue;
    for (int dx = 0; dx < 3; ++dx){
      int xx = x + dx - 1;
      if ((unsigned)xx >= (unsigned)W) continue;
      long long wbase = ((long long)(dy*3+dx)*Ci)*Co + co;
      long long sb = ((long long)b*H + yy)*(long long)W + xx;
      const bf16* ip0 = in0 + sb*(long long)C0;
      for (int c = 0; c < C0; ++c)
        acc += b2f(ip0[c]) * ldv<TW>(w, wbase + (long long)c*Co);
      if (in1){
        const bf16* ip1 = in1 + sb*(long long)C1;
        for (int c = 0; c < C1; ++c)
          acc += b2f(ip1[c]) * ldv<TW>(w, wbase + (long long)(C0+c)*Co);
      }
    }
  }
  stv<TO>(out, out_off + idx, acc);
}

__global__ void k_conv3_mid(const int* __restrict__ flag, const bf16* in0, int C0, const bf16* in1, int C1,
    const void* w, const unsigned char* mask, bf16* out, int B,int H,int W,int Co){
  if (*flag) conv3_body<float,bf16>(in0,C0,in1,C1,w,mask,out,0,B,H,W,Co);
  else       conv3_body<bf16 ,bf16>(in0,C0,in1,C1,w,mask,out,0,B,H,W,Co);
}

__global__ void k_conv3_out(const int* __restrict__ flag, const bf16* in0, int C0, const bf16* in1, int C1,
    const void* w, const unsigned char* mask, void* out, long long out_off, int B,int H,int W,int Co){
  if (*flag) conv3_body<float,float>(in0,C0,in1,C1,w,mask,out,out_off,B,H,W,Co);
  else       conv3_body<bf16 ,bf16 >(in0,C0,in1,C1,w,mask,out,out_off,B,H,W,Co);
}

// convert a region of d_out (dtype per flag) into a bf16 ws buffer
__global__ void k_cvt(const int* __restrict__ flag, const void* __restrict__ src, long long src_off,
                      bf16* __restrict__ dst, long long n){
  long long i = blockIdx.x*(long long)blockDim.x + threadIdx.x;
  if (i >= n) return;
  float v = (*flag) ? ldv<float>(src, src_off+i) : ldv<bf16>(src, src_off+i);
  dst[i] = f2b(v);
}

// ---------------- masked 2x2 stride-2 maxpool ----------------
__global__ void k_pool(const bf16* __restrict__ in, const unsigned char* __restrict__ mi,
                       bf16* __restrict__ out, unsigned char* __restrict__ mo,
                       int B, int Ho, int Wo, int C){
  long long idx = blockIdx.x*(long long)blockDim.x + threadIdx.x;
  long long total = (long long)B*Ho*Wo*C;
  if (idx >= total) return;
  int c = (int)(idx % C);
  long long s = idx / C;
  int x = (int)(s % Wo);
  long long t = s / Wo;
  int y = (int)(t % Ho);
  int b = (int)(t / Ho);
  int Hi = Ho*2, Wi = Wo*2;
  float best = -3.4e38f;
  bool any = false;
  for (int a = 0; a < 2; ++a){
    for (int d = 0; d < 2; ++d){
      long long site = ((long long)b*Hi + (2*y+a))*(long long)Wi + (2*x+d);
      if (mi[site]){
        any = true;
        best = fmaxf(best, b2f(in[site*(long long)C + c]));
      }
    }
  }
  out[idx] = any ? f2b(best) : f2b(0.f);
  if (c == 0) mo[s] = (unsigned char)any;
}

// ---------------- 2x2 stride-2 transpose conv (zeros propagate) ----------------
template<typename TW>
__device__ __forceinline__ void tconv_body(const bf16* __restrict__ in, const void* __restrict__ w,
    bf16* __restrict__ out, int B, int Hi, int Wi, int Ci, int Co){
  long long idx = blockIdx.x*(long long)blockDim.x + threadIdx.x;
  int Ho = Hi*2, Wo = Wi*2;
  long long total = (long long)B*Ho*Wo*Co;
  if (idx >= total) return;
  int co = (int)(idx % Co);
  long long s = idx / Co;
  int ox = (int)(s % Wo);
  long long t = s / Wo;
  int oy = (int)(t % Ho);
  int b = (int)(t / Ho);
  int iy = oy >> 1, ix = ox >> 1;
  int di = oy & 1, dj = ox & 1;
  long long wbase = ((long long)(di*2+dj)*Ci)*Co + co;
  const bf16* ip = in + (((long long)b*Hi + iy)*(long long)Wi + ix)*(long long)Ci;
  float acc = 0.f;
  for (int c = 0; c < Ci; ++c)
    acc += b2f(ip[c]) * ldv<TW>(w, wbase + (long long)c*Co);
  out[idx] = f2b(acc);
}

__global__ void k_tconv(const int* __restrict__ flag, const bf16* in, const void* w, bf16* out,
                        int B,int Hi,int Wi,int Ci,int Co){
  if (*flag) tconv_body<float>(in,w,out,B,Hi,Wi,Ci,Co);
  else       tconv_body<bf16 >(in,w,out,B,Hi,Wi,Ci,Co);
}

// ---------------- 1x1 conv head, masked, writes output dtype ----------------
template<typename TW, typename TO>
__device__ __forceinline__ void conv1_body(const bf16* __restrict__ in, const void* __restrict__ w,
    const unsigned char* __restrict__ mask, void* __restrict__ out,
    int B,int H,int W,int Ci,int Co){
  long long idx = blockIdx.x*(long long)blockDim.x + threadIdx.x;
  long long total = (long long)B*H*W*Co;
  if (idx >= total) return;
  int co = (int)(idx % Co);
  long long s = idx / Co;
  if (!mask[s]){ stv<TO>(out, idx, 0.f); return; }
  const bf16* ip = in + s*(long long)Ci;
  float acc = 0.f;
  for (int c = 0; c < Ci; ++c)
    acc += b2f(ip[c]) * ldv<TW>(w, (long long)c*Co + co);
  stv<TO>(out, idx, acc);
}

__global__ void k_conv1_out(const int* __restrict__ flag, const bf16* in, const void* w,
    const unsigned char* mask, void* out, int B,int H,int W,int Ci,int Co){
  if (*flag) conv1_body<float,float>(in,w,mask,out,B,H,W,Ci,Co);
  else       conv1_body<bf16 ,bf16 >(in,w,mask,out,B,H,W,Ci,Co);
}

// ---------------- host side ----------------
static inline dim3 grid1d(long long total, int block){
  return dim3((unsigned)((total + block - 1) / block));
}

extern "C" void kernel_launch(void* const* d_in, const int* in_sizes, int n_in,
                              void* d_out, int out_size, void* d_ws, size_t ws_size,
                              hipStream_t stream) {
  const void* x    = d_in[0];
  const int* mask  = (const int*)d_in[1];
  const void* w_ds1=d_in[2], *w_ds2=d_in[3], *w_ds3=d_in[4], *w_ds4=d_in[5];
  const void* w_bridge=d_in[6];
  const void* wt4=d_in[7], *w_us4=d_in[8], *wt3=d_in[9], *w_us3=d_in[10];
  const void* wt2=d_in[11], *w_us2=d_in[12], *wt1=d_in[13], *w_us1=d_in[14];
  const void* w_out=d_in[15];

  const long long C2_OFF = (long long)2*1024*1024*3;   // element offset of c2 in d_out
  const int B = 2;

  // ws layout: [flag(16B pad)][bf16 arena][mask arena]
  int* flag = (int*)d_ws;
  bf16* wsb = (bf16*)((char*)d_ws + 16);
  long long off = 0;
  bf16* xm   = wsb + off; off += (long long)2*1024*1024*1;
  bf16* c1   = wsb + off; off += (long long)2*1024*1024*16;
  bf16* c2b  = wsb + off; off += (long long)2*512*512*32;
  bf16* c3   = wsb + off; off += (long long)2*256*256*64;
  bf16* c4   = wsb + off; off += (long long)2*128*128*128;
  bf16* ping = wsb + off; off += (long long)2*1024*1024*16;
  bf16* pong = wsb + off; off += (long long)2*1024*1024*16;
  unsigned char* mb = (unsigned char*)(wsb + off);
  long long mo = 0;
  unsigned char* m0u = mb + mo; mo += (long long)2*1024*1024;
  unsigned char* m1  = mb + mo; mo += (long long)2*512*512;
  unsigned char* m2  = mb + mo; mo += (long long)2*256*256;
  unsigned char* m3  = mb + mo; mo += (long long)2*128*128;
  unsigned char* m4  = mb + mo; mo += (long long)2*64*64;
  unsigned char* mc4 = mb + mo; mo += (long long)2*128*128;
  unsigned char* mc3 = mb + mo; mo += (long long)2*256*256;
  unsigned char* mc2 = mb + mo; mo += (long long)2*512*512;
  unsigned char* mc1 = mb + mo; mo += (long long)2*1024*1024;

  const int BK = 256;
  long long n;

  // dtype detection + prep
  k_zero_flag<<<1,1,0,stream>>>(flag);
  n = (long long)B*1024*1024;
  k_detect<<<grid1d(n,BK),BK,0,stream>>>((const unsigned short*)x, n, flag);
  k_prep  <<<grid1d(n,BK),BK,0,stream>>>(x, mask, flag, xm, m0u, n);

  // encoder
  n = (long long)B*1024*1024*16;
  k_conv3_mid<<<grid1d(n,BK),BK,0,stream>>>(flag, xm,1, nullptr,0, w_ds1, m0u, c1, B,1024,1024,16);
  n = (long long)B*512*512*16;
  k_pool<<<grid1d(n,BK),BK,0,stream>>>(c1, m0u, ping, m1, B,512,512,16);
  n = (long long)B*512*512*32;
  k_conv3_out<<<grid1d(n,BK),BK,0,stream>>>(flag, ping,16, nullptr,0, w_ds2, m1, d_out, C2_OFF, B,512,512,32);
  k_cvt<<<grid1d(n,BK),BK,0,stream>>>(flag, d_out, C2_OFF, c2b, n);
  n = (long long)B*256*256*32;
  k_pool<<<grid1d(n,BK),BK,0,stream>>>(c2b, m1, ping, m2, B,256,256,32);
  n = (long long)B*256*256*64;
  k_conv3_mid<<<grid1d(n,BK),BK,0,stream>>>(flag, ping,32, nullptr,0, w_ds3, m2, c3, B,256,256,64);
  n = (long long)B*128*128*64;
  k_pool<<<grid1d(n,BK),BK,0,stream>>>(c3, m2, ping, m3, B,128,128,64);
  n = (long long)B*128*128*128;
  k_conv3_mid<<<grid1d(n,BK),BK,0,stream>>>(flag, ping,64, nullptr,0, w_ds4, m3, c4, B,128,128,128);
  n = (long long)B*64*64*128;
  k_pool<<<grid1d(n,BK),BK,0,stream>>>(c4, m3, ping, m4, B,64,64,128);

  // bridge
  n = (long long)B*64*64*256;
  k_conv3_mid<<<grid1d(n,BK),BK,0,stream>>>(flag, ping,128, nullptr,0, w_bridge, m4, pong, B,64,64,256);

  // decoder 4
  n = (long long)B*128*128*128;
  k_tconv<<<grid1d(n,BK),BK,0,stream>>>(flag, pong, wt4, ping, B,64,64,256,128);
  n = (long long)B*128*128;
  k_mask_comb<<<grid1d(n,BK),BK,0,stream>>>(m4, m3, mc4, B,128,128);
  n = (long long)B*128*128*128;
  k_conv3_mid<<<grid1d(n,BK),BK,0,stream>>>(flag, ping,128, c4,128, w_us4, mc4, pong, B,128,128,128);

  // decoder 3
  n = (long long)B*256*256*64;
  k_tconv<<<grid1d(n,BK),BK,0,stream>>>(flag, pong, wt3, ping, B,128,128,128,64);
  n = (long long)B*256*256;
  k_mask_comb<<<grid1d(n,BK),BK,0,stream>>>(mc4, m2, mc3, B,256,256);
  n = (long long)B*256*256*64;
  k_conv3_mid<<<grid1d(n,BK),BK,0,stream>>>(flag, ping,64, c3,64, w_us3, mc3, pong, B,256,256,64);

  // decoder 2
  n = (long long)B*512*512*32;
  k_tconv<<<grid1d(n,BK),BK,0,stream>>>(flag, pong, wt2, ping, B,256,256,64,32);
  n = (long long)B*512*512;
  k_mask_comb<<<grid1d(n,BK),BK,0,stream>>>(mc3, m1, mc2, B,512,512);
  n = (long long)B*512*512*32;
  k_conv3_mid<<<grid1d(n,BK),BK,0,stream>>>(flag, ping,32, c2b,32, w_us2, mc2, pong, B,512,512,32);

  // decoder 1
  n = (long long)B*1024*1024*16;
  k_tconv<<<grid1d(n,BK),BK,0,stream>>>(flag, pong, wt1, ping, B,512,512,32,16);
  n = (long long)B*1024*1024;
  k_mask_comb<<<grid1d(n,BK),BK,0,stream>>>(mc2, m0u, mc1, B,1024,1024);
  n = (long long)B*1024*1024*16;
  k_conv3_mid<<<grid1d(n,BK),BK,0,stream>>>(flag, ping,16, c1,16, w_us1, mc1, pong, B,1024,1024,16);

  // head
  n = (long long)B*1024*1024*3;
  k_conv1_out<<<grid1d(n,BK),BK,0,stream>>>(flag, pong, w_out, mc1, d_out, B,1024,1024,16,3);
}

// Round 3
// 2852.599 us; speedup vs baseline: 4.9526x; 4.9526x over previous
//
#include <hip/hip_runtime.h>
#include <hip/hip_bf16.h>

using bf16 = __hip_bfloat16;
typedef __bf16 bf8 __attribute__((ext_vector_type(8)));
typedef float  f4  __attribute__((ext_vector_type(4)));

__device__ __forceinline__ float b2f(bf16 v){ return __bfloat162float(v); }
__device__ __forceinline__ bf16 f2b(float v){ return __float2bfloat16(v); }

template<typename T> __device__ __forceinline__ float ldv(const void* p, long long i);
template<> __device__ __forceinline__ float ldv<float>(const void* p, long long i){ return ((const float*)p)[i]; }
template<> __device__ __forceinline__ float ldv<bf16 >(const void* p, long long i){ return b2f(((const bf16*)p)[i]); }

template<typename T> __device__ __forceinline__ void stv(void* p, long long i, float v);
template<> __device__ __forceinline__ void stv<float>(void* p, long long i, float v){ ((float*)p)[i] = v; }
template<> __device__ __forceinline__ void stv<bf16 >(void* p, long long i, float v){ ((bf16*)p)[i] = f2b(v); }

// ---------------- dtype detection ----------------
__global__ void k_zero_flag(int* f){ *f = 0; }

__global__ void k_detect(const unsigned short* __restrict__ x, long long n, int* __restrict__ flag){
  long long i = blockIdx.x*(long long)blockDim.x + threadIdx.x;
  if (i >= n) return;
  unsigned short u = x[i];
  if ((u & 0x7F80u) == 0x7F80u) atomicOr(flag, 1);
}

// ---------------- prep ----------------
__global__ void k_prep(const void* __restrict__ x, const int* __restrict__ m, const int* __restrict__ flag,
                       bf16* __restrict__ xo, unsigned char* __restrict__ mo, long long n){
  long long i = blockIdx.x*(long long)blockDim.x + threadIdx.x;
  if (i >= n) return;
  int f = *flag;
  int mm = (m[i] != 0);
  mo[i] = (unsigned char)mm;
  float v = f ? ldv<float>(x, i) : ldv<bf16>(x, i);
  xo[i] = f2b(mm ? v : 0.f);
}

__global__ void k_mask_comb(const unsigned char* __restrict__ coarse,
                            const unsigned char* __restrict__ fine,
                            unsigned char* __restrict__ mo,
                            int B, int H, int W){
  long long i = blockIdx.x*(long long)blockDim.x + threadIdx.x;
  long long total = (long long)B*H*W;
  if (i >= total) return;
  int x = (int)(i % W);
  long long t = i / W;
  int y = (int)(t % H);
  int b = (int)(t / H);
  unsigned char c = coarse[((long long)b*(H/2) + (y>>1))*(W/2) + (x>>1)];
  mo[i] = (unsigned char)(c | fine[i]);
}

// ---------------- weight transform: [taps][Ci][Co] (flag dtype) -> bf16 [taps][Co][Cip], zero-padded ----------------
__global__ void k_wt(const int* __restrict__ flag, const void* __restrict__ w, bf16* __restrict__ wt,
                     int taps, int Ci, int Co, int Cip){
  long long i = blockIdx.x*(long long)blockDim.x + threadIdx.x;
  long long total = (long long)taps*Co*Cip;
  if (i >= total) return;
  int ci = (int)(i % Cip);
  long long t2 = i / Cip;
  int co = (int)(t2 % Co);
  int tap = (int)(t2 / Co);
  float v = 0.f;
  if (ci < Ci){
    long long src = ((long long)tap*Ci + ci)*Co + co;
    v = (*flag) ? ldv<float>(w, src) : ldv<bf16>(w, src);
  }
  wt[i] = f2b(v);
}

// ---------------- MFMA implicit-GEMM conv3x3 ----------------
// Wave: 16 sites (consecutive x) x (16*COT) co.  A: in[site, ci] direct global;
// B: wt[tap][co][Cip] direct global.  A frag: A[m=lane&15][k=quad*8+j];
// B frag: B[k=quad*8+j][n=lane&15]; D: row=quad*4+r (site), col=lane&15 (co).
template<int COT>
__global__ __launch_bounds__(256)
void k_conv3_mfma(const bf16* __restrict__ in0, int C0,
                  const bf16* __restrict__ in1, int C1,
                  const bf16* __restrict__ wt, int Cip,
                  const unsigned char* __restrict__ mask,
                  void* __restrict__ out, long long out_off,
                  const int* __restrict__ flag, int use_flag,
                  int B, int H, int W, int Co, int cotiles){
  int lane = threadIdx.x & 63;
  int wid  = threadIdx.x >> 6;
  int n16  = lane & 15, quad = lane >> 4;
  int x0 = (blockIdx.x*4 + wid)*16;
  int y  = blockIdx.y;
  int b  = blockIdx.z / cotiles;
  int ct = blockIdx.z % cotiles;
  int co0 = ct * (16*COT);
  int Citot = C0 + C1;

  f4 acc[COT];
  #pragma unroll
  for (int j = 0; j < COT; ++j) acc[j] = (f4){0.f,0.f,0.f,0.f};

  bf8 az;
  #pragma unroll
  for (int i = 0; i < 8; ++i) az[i] = (__bf16)0.f;

  int x = x0 + n16;
  for (int dy = 0; dy < 3; ++dy){
    int yy = y + dy - 1;
    if ((unsigned)yy >= (unsigned)H) continue;       // block-uniform
    long long rowb = ((long long)b*H + yy)*(long long)W;
    for (int dx = 0; dx < 3; ++dx){
      int xx = x + dx - 1;
      bool xok = (unsigned)xx < (unsigned)W;
      long long sb = rowb + xx;
      int tap = dy*3 + dx;
      for (int k0 = 0; k0 < Cip; k0 += 32){
        int c = k0 + quad*8;
        bf8 a = az;
        if (xok && c < Citot){
          a = (c < C0) ? *(const bf8*)(const void*)(in0 + sb*(long long)C0 + c)
                       : *(const bf8*)(const void*)(in1 + sb*(long long)C1 + (c - C0));
        }
        #pragma unroll
        for (int j = 0; j < COT; ++j){
          bf8 bfrag = *(const bf8*)(const void*)(wt + ((long long)(tap*Co + co0 + j*16 + n16))*Cip + k0 + quad*8);
          acc[j] = __builtin_amdgcn_mfma_f32_16x16x32_bf16(a, bfrag, acc[j], 0, 0, 0);
        }
      }
    }
  }

  int f = use_flag ? *flag : 0;
  long long srow = ((long long)b*H + y)*(long long)W;
  #pragma unroll
  for (int j = 0; j < COT; ++j){
    #pragma unroll
    for (int r = 0; r < 4; ++r){
      int sx = x0 + quad*4 + r;
      long long s = srow + sx;
      float v = mask[s] ? acc[j][r] : 0.f;
      long long o = out_off + s*(long long)Co + co0 + j*16 + n16;
      if (f) ((float*)out)[o] = v;
      else   ((bf16*)out)[o]  = f2b(v);
    }
  }
}

// ---------------- scalar conv3 (kept for ds1, Ci=1) ----------------
template<typename TW, typename TO>
__device__ __forceinline__ void conv3_body(const bf16* __restrict__ in0, int C0,
    const bf16* __restrict__ in1, int C1, const void* __restrict__ w,
    const unsigned char* __restrict__ mask, void* __restrict__ out, long long out_off,
    int B, int H, int W, int Co){
  long long idx = blockIdx.x*(long long)blockDim.x + threadIdx.x;
  long long total = (long long)B*H*W*Co;
  if (idx >= total) return;
  int co = (int)(idx % Co);
  long long s = idx / Co;
  int x = (int)(s % W);
  long long t = s / W;
  int y = (int)(t % H);
  int b = (int)(t / H);
  if (!mask[s]){ stv<TO>(out, out_off + idx, 0.f); return; }
  const int Ci = C0 + C1;
  float acc = 0.f;
  for (int dy = 0; dy < 3; ++dy){
    int yy = y + dy - 1;
    if ((unsigned)yy >= (unsigned)H) continue;
    for (int dx = 0; dx < 3; ++dx){
      int xx = x + dx - 1;
      if ((unsigned)xx >= (unsigned)W) continue;
      long long wbase = ((long long)(dy*3+dx)*Ci)*Co + co;
      long long sb = ((long long)b*H + yy)*(long long)W + xx;
      const bf16* ip0 = in0 + sb*(long long)C0;
      for (int c = 0; c < C0; ++c)
        acc += b2f(ip0[c]) * ldv<TW>(w, wbase + (long long)c*Co);
    }
  }
  stv<TO>(out, out_off + idx, acc);
}

__global__ void k_conv3_mid(const int* __restrict__ flag, const bf16* in0, int C0, const bf16* in1, int C1,
    const void* w, const unsigned char* mask, bf16* out, int B,int H,int W,int Co){
  if (*flag) conv3_body<float,bf16>(in0,C0,in1,C1,w,mask,out,0,B,H,W,Co);
  else       conv3_body<bf16 ,bf16>(in0,C0,in1,C1,w,mask,out,0,B,H,W,Co);
}

__global__ void k_cvt(const int* __restrict__ flag, const void* __restrict__ src, long long src_off,
                      bf16* __restrict__ dst, long long n){
  long long i = blockIdx.x*(long long)blockDim.x + threadIdx.x;
  if (i >= n) return;
  float v = (*flag) ? ldv<float>(src, src_off+i) : ldv<bf16>(src, src_off+i);
  dst[i] = f2b(v);
}

// ---------------- masked 2x2 stride-2 maxpool ----------------
__global__ void k_pool(const bf16* __restrict__ in, const unsigned char* __restrict__ mi,
                       bf16* __restrict__ out, unsigned char* __restrict__ mo,
                       int B, int Ho, int Wo, int C){
  long long idx = blockIdx.x*(long long)blockDim.x + threadIdx.x;
  long long total = (long long)B*Ho*Wo*C;
  if (idx >= total) return;
  int c = (int)(idx % C);
  long long s = idx / C;
  int x = (int)(s % Wo);
  long long t = s / Wo;
  int y = (int)(t % Ho);
  int b = (int)(t / Ho);
  int Hi = Ho*2, Wi = Wo*2;
  float best = -3.4e38f;
  bool any = false;
  for (int a = 0; a < 2; ++a){
    for (int d = 0; d < 2; ++d){
      long long site = ((long long)b*Hi + (2*y+a))*(long long)Wi + (2*x+d);
      if (mi[site]){
        any = true;
        best = fmaxf(best, b2f(in[site*(long long)C + c]));
      }
    }
  }
  out[idx] = any ? f2b(best) : f2b(0.f);
  if (c == 0) mo[s] = (unsigned char)any;
}

// ---------------- 2x2 stride-2 transpose conv ----------------
template<typename TW>
__device__ __forceinline__ void tconv_body(const bf16* __restrict__ in, const void* __restrict__ w,
    bf16* __restrict__ out, int B, int Hi, int Wi, int Ci, int Co){
  long long idx = blockIdx.x*(long long)blockDim.x + threadIdx.x;
  int Ho = Hi*2, Wo = Wi*2;
  long long total = (long long)B*Ho*Wo*Co;
  if (idx >= total) return;
  int co = (int)(idx % Co);
  long long s = idx / Co;
  int ox = (int)(s % Wo);
  long long t = s / Wo;
  int oy = (int)(t % Ho);
  int b = (int)(t / Ho);
  int iy = oy >> 1, ix = ox >> 1;
  int di = oy & 1, dj = ox & 1;
  long long wbase = ((long long)(di*2+dj)*Ci)*Co + co;
  const bf16* ip = in + (((long long)b*Hi + iy)*(long long)Wi + ix)*(long long)Ci;
  float acc = 0.f;
  for (int c = 0; c < Ci; ++c)
    acc += b2f(ip[c]) * ldv<TW>(w, wbase + (long long)c*Co);
  out[idx] = f2b(acc);
}

__global__ void k_tconv(const int* __restrict__ flag, const bf16* in, const void* w, bf16* out,
                        int B,int Hi,int Wi,int Ci,int Co){
  if (*flag) tconv_body<float>(in,w,out,B,Hi,Wi,Ci,Co);
  else       tconv_body<bf16 >(in,w,out,B,Hi,Wi,Ci,Co);
}

// ---------------- 1x1 conv head ----------------
template<typename TW, typename TO>
__device__ __forceinline__ void conv1_body(const bf16* __restrict__ in, const void* __restrict__ w,
    const unsigned char* __restrict__ mask, void* __restrict__ out,
    int B,int H,int W,int Ci,int Co){
  long long idx = blockIdx.x*(long long)blockDim.x + threadIdx.x;
  long long total = (long long)B*H*W*Co;
  if (idx >= total) return;
  int co = (int)(idx % Co);
  long long s = idx / Co;
  if (!mask[s]){ stv<TO>(out, idx, 0.f); return; }
  const bf16* ip = in + s*(long long)Ci;
  float acc = 0.f;
  for (int c = 0; c < Ci; ++c)
    acc += b2f(ip[c]) * ldv<TW>(w, (long long)c*Co + co);
  stv<TO>(out, idx, acc);
}

__global__ void k_conv1_out(const int* __restrict__ flag, const bf16* in, const void* w,
    const unsigned char* mask, void* out, int B,int H,int W,int Ci,int Co){
  if (*flag) conv1_body<float,float>(in,w,mask,out,B,H,W,Ci,Co);
  else       conv1_body<bf16 ,bf16 >(in,w,mask,out,B,H,W,Ci,Co);
}

// ---------------- host side ----------------
static inline dim3 grid1d(long long total, int block){
  return dim3((unsigned)((total + block - 1) / block));
}

extern "C" void kernel_launch(void* const* d_in, const int* in_sizes, int n_in,
                              void* d_out, int out_size, void* d_ws, size_t ws_size,
                              hipStream_t stream) {
  const void* x    = d_in[0];
  const int* mask  = (const int*)d_in[1];
  const void* w_ds1=d_in[2], *w_ds2=d_in[3], *w_ds3=d_in[4], *w_ds4=d_in[5];
  const void* w_bridge=d_in[6];
  const void* wt4=d_in[7], *w_us4=d_in[8], *wt3=d_in[9], *w_us3=d_in[10];
  const void* wt2=d_in[11], *w_us2=d_in[12], *wt1=d_in[13], *w_us1=d_in[14];
  const void* w_out=d_in[15];

  const long long C2_OFF = (long long)2*1024*1024*3;
  const int B = 2;

  int* flag = (int*)d_ws;
  bf16* wsb = (bf16*)((char*)d_ws + 16);
  long long off = 0;
  bf16* xm   = wsb + off; off += (long long)2*1024*1024*1;
  bf16* c1   = wsb + off; off += (long long)2*1024*1024*16;
  bf16* c2b  = wsb + off; off += (long long)2*512*512*32;
  bf16* c3   = wsb + off; off += (long long)2*256*256*64;
  bf16* c4   = wsb + off; off += (long long)2*128*128*128;
  bf16* ping = wsb + off; off += (long long)2*1024*1024*16;
  bf16* pong = wsb + off; off += (long long)2*1024*1024*16;
  // transposed bf16 weights [taps][Co][Cip]
  bf16* wtds2 = wsb + off; off += (long long)9*32*32;
  bf16* wtds3 = wsb + off; off += (long long)9*64*32;
  bf16* wtds4 = wsb + off; off += (long long)9*128*64;
  bf16* wtbr  = wsb + off; off += (long long)9*256*128;
  bf16* wtus4 = wsb + off; off += (long long)9*128*256;
  bf16* wtus3 = wsb + off; off += (long long)9*64*128;
  bf16* wtus2 = wsb + off; off += (long long)9*32*64;
  bf16* wtus1 = wsb + off; off += (long long)9*16*32;
  unsigned char* mb = (unsigned char*)(wsb + off);
  long long mo = 0;
  unsigned char* m0u = mb + mo; mo += (long long)2*1024*1024;
  unsigned char* m1  = mb + mo; mo += (long long)2*512*512;
  unsigned char* m2  = mb + mo; mo += (long long)2*256*256;
  unsigned char* m3  = mb + mo; mo += (long long)2*128*128;
  unsigned char* m4  = mb + mo; mo += (long long)2*64*64;
  unsigned char* mc4 = mb + mo; mo += (long long)2*128*128;
  unsigned char* mc3 = mb + mo; mo += (long long)2*256*256;
  unsigned char* mc2 = mb + mo; mo += (long long)2*512*512;
  unsigned char* mc1 = mb + mo; mo += (long long)2*1024*1024;

  const int BK = 256;
  long long n;

  // dtype detection + prep
  k_zero_flag<<<1,1,0,stream>>>(flag);
  n = (long long)B*1024*1024;
  k_detect<<<grid1d(n,BK),BK,0,stream>>>((const unsigned short*)x, n, flag);
  k_prep  <<<grid1d(n,BK),BK,0,stream>>>(x, mask, flag, xm, m0u, n);

  // weight transforms (taps=9): (Ci, Co, Cip)
  k_wt<<<grid1d((long long)9*32*32 ,BK),BK,0,stream>>>(flag, w_ds2,   wtds2, 9,  16,  32,  32);
  k_wt<<<grid1d((long long)9*64*32 ,BK),BK,0,stream>>>(flag, w_ds3,   wtds3, 9,  32,  64,  32);
  k_wt<<<grid1d((long long)9*128*64,BK),BK,0,stream>>>(flag, w_ds4,   wtds4, 9,  64, 128,  64);
  k_wt<<<grid1d((long long)9*256*128,BK),BK,0,stream>>>(flag, w_bridge,wtbr , 9, 128, 256, 128);
  k_wt<<<grid1d((long long)9*128*256,BK),BK,0,stream>>>(flag, w_us4,  wtus4, 9, 256, 128, 256);
  k_wt<<<grid1d((long long)9*64*128,BK),BK,0,stream>>>(flag, w_us3,   wtus3, 9, 128,  64, 128);
  k_wt<<<grid1d((long long)9*32*64 ,BK),BK,0,stream>>>(flag, w_us2,   wtus2, 9,  64,  32,  64);
  k_wt<<<grid1d((long long)9*16*32 ,BK),BK,0,stream>>>(flag, w_us1,   wtus1, 9,  32,  16,  32);

  // ds1 (Ci=1) scalar
  n = (long long)B*1024*1024*16;
  k_conv3_mid<<<grid1d(n,BK),BK,0,stream>>>(flag, xm,1, nullptr,0, w_ds1, m0u, c1, B,1024,1024,16);
  n = (long long)B*512*512*16;
  k_pool<<<grid1d(n,BK),BK,0,stream>>>(c1, m0u, ping, m1, B,512,512,16);

  // ds2 (MFMA) -> d_out (c2), then cvt to c2b
  k_conv3_mfma<2><<<dim3(512/64,512,B*1),256,0,stream>>>(ping,16, nullptr,0, wtds2,32, m1, d_out, C2_OFF, flag,1, B,512,512,32, 1);
  n = (long long)B*512*512*32;
  k_cvt<<<grid1d(n,BK),BK,0,stream>>>(flag, d_out, C2_OFF, c2b, n);
  n = (long long)B*256*256*32;
  k_pool<<<grid1d(n,BK),BK,0,stream>>>(c2b, m1, ping, m2, B,256,256,32);

  // ds3
  k_conv3_mfma<2><<<dim3(256/64,256,B*2),256,0,stream>>>(ping,32, nullptr,0, wtds3,32, m2, c3, 0, flag,0, B,256,256,64, 2);
  n = (long long)B*128*128*64;
  k_pool<<<grid1d(n,BK),BK,0,stream>>>(c3, m2, ping, m3, B,128,128,64);

  // ds4
  k_conv3_mfma<2><<<dim3(128/64,128,B*4),256,0,stream>>>(ping,64, nullptr,0, wtds4,64, m3, c4, 0, flag,0, B,128,128,128, 4);
  n = (long long)B*64*64*128;
  k_pool<<<grid1d(n,BK),BK,0,stream>>>(c4, m3, ping, m4, B,64,64,128);

  // bridge
  k_conv3_mfma<2><<<dim3(64/64,64,B*8),256,0,stream>>>(ping,128, nullptr,0, wtbr,128, m4, pong, 0, flag,0, B,64,64,256, 8);

  // decoder 4
  k_tconv<<<grid1d((long long)B*128*128*128,BK),BK,0,stream>>>(flag, pong, wt4, ping, B,64,64,256,128);
  n = (long long)B*128*128;
  k_mask_comb<<<grid1d(n,BK),BK,0,stream>>>(m4, m3, mc4, B,128,128);
  k_conv3_mfma<2><<<dim3(128/64,128,B*4),256,0,stream>>>(ping,128, c4,128, wtus4,256, mc4, pong, 0, flag,0, B,128,128,128, 4);

  // decoder 3
  k_tconv<<<grid1d((long long)B*256*256*64,BK),BK,0,stream>>>(flag, pong, wt3, ping, B,128,128,128,64);
  n = (long long)B*256*256;
  k_mask_comb<<<grid1d(n,BK),BK,0,stream>>>(mc4, m2, mc3, B,256,256);
  k_conv3_mfma<2><<<dim3(256/64,256,B*2),256,0,stream>>>(ping,64, c3,64, wtus3,128, mc3, pong, 0, flag,0, B,256,256,64, 2);

  // decoder 2
  k_tconv<<<grid1d((long long)B*512*512*32,BK),BK,0,stream>>>(flag, pong, wt2, ping, B,256,256,64,32);
  n = (long long)B*512*512;
  k_mask_comb<<<grid1d(n,BK),BK,0,stream>>>(mc3, m1, mc2, B,512,512);
  k_conv3_mfma<2><<<dim3(512/64,512,B*1),256,0,stream>>>(ping,32, c2b,32, wtus2,64, mc2, pong, 0, flag,0, B,512,512,32, 1);

  // decoder 1
  k_tconv<<<grid1d((long long)B*1024*1024*16,BK),BK,0,stream>>>(flag, pong, wt1, ping, B,512,512,32,16);
  n = (long long)B*1024*1024;
  k_mask_comb<<<grid1d(n,BK),BK,0,stream>>>(mc2, m0u, mc1, B,1024,1024);
  k_conv3_mfma<1><<<dim3(1024/64,1024,B*1),256,0,stream>>>(ping,16, c1,16, wtus1,32, mc1, pong, 0, flag,0, B,1024,1024,16, 1);

  // head
  n = (long long)B*1024*1024*3;
  k_conv1_out<<<grid1d(n,BK),BK,0,stream>>>(flag, pong, w_out, mc1, d_out, B,1024,1024,16,3);
}

// Round 4
// 1298.258 us; speedup vs baseline: 10.8820x; 2.1973x over previous
//
#include <hip/hip_runtime.h>
#include <hip/hip_bf16.h>

using bf16 = __hip_bfloat16;
typedef __bf16 bf8 __attribute__((ext_vector_type(8)));
typedef float  f4  __attribute__((ext_vector_type(4)));

__device__ __forceinline__ float b2f(bf16 v){ return __bfloat162float(v); }
__device__ __forceinline__ bf16 f2b(float v){ return __float2bfloat16(v); }

template<typename T> __device__ __forceinline__ float ldv(const void* p, long long i);
template<> __device__ __forceinline__ float ldv<float>(const void* p, long long i){ return ((const float*)p)[i]; }
template<> __device__ __forceinline__ float ldv<bf16 >(const void* p, long long i){ return b2f(((const bf16*)p)[i]); }

// ---------------- dtype detection ----------------
__global__ void k_zero_flag(int* f){ *f = 0; }

__global__ void k_detect(const unsigned short* __restrict__ x, long long n, int* __restrict__ flag){
  long long i = blockIdx.x*(long long)blockDim.x + threadIdx.x;
  if (i >= n) return;
  unsigned short u = x[i];
  if ((u & 0x7F80u) == 0x7F80u) atomicOr(flag, 1);
}

// ---------------- prep ----------------
__global__ void k_prep(const void* __restrict__ x, const int* __restrict__ m, const int* __restrict__ flag,
                       bf16* __restrict__ xo, unsigned char* __restrict__ mo, long long n){
  long long i = blockIdx.x*(long long)blockDim.x + threadIdx.x;
  if (i >= n) return;
  int f = *flag;
  int mm = (m[i] != 0);
  mo[i] = (unsigned char)mm;
  float v = f ? ldv<float>(x, i) : ldv<bf16>(x, i);
  xo[i] = f2b(mm ? v : 0.f);
}

__global__ void k_mask_comb(const unsigned char* __restrict__ coarse,
                            const unsigned char* __restrict__ fine,
                            unsigned char* __restrict__ mo,
                            int B, int H, int W){
  long long i = blockIdx.x*(long long)blockDim.x + threadIdx.x;
  long long total = (long long)B*H*W;
  if (i >= total) return;
  int x = (int)(i % W);
  long long t = i / W;
  int y = (int)(t % H);
  int b = (int)(t / H);
  unsigned char c = coarse[((long long)b*(H/2) + (y>>1))*(W/2) + (x>>1)];
  mo[i] = (unsigned char)(c | fine[i]);
}

// ---------------- weight transform: [taps][Ci][Co] (flag dtype) -> bf16 [taps][Co][Cip] ----------------
__global__ void k_wt(const int* __restrict__ flag, const void* __restrict__ w, bf16* __restrict__ wt,
                     int taps, int Ci, int Co, int Cip){
  long long i = blockIdx.x*(long long)blockDim.x + threadIdx.x;
  long long total = (long long)taps*Co*Cip;
  if (i >= total) return;
  int ci = (int)(i % Cip);
  long long t2 = i / Cip;
  int co = (int)(t2 % Co);
  int tap = (int)(t2 / Co);
  float v = 0.f;
  if (ci < Ci){
    long long src = ((long long)tap*Ci + ci)*Co + co;
    v = (*flag) ? ldv<float>(w, src) : ldv<bf16>(w, src);
  }
  wt[i] = f2b(v);
}

// ---------------- MFMA implicit-GEMM conv3x3 ----------------
// Wave: 16 sites (consecutive x) x (16*COT) co.  A frag: A[m=lane&15][k=quad*8+j];
// B frag from wt[tap][co][Cip]; D: row=quad*4+r (site), col=lane&15 (co).
template<int COT>
__global__ __launch_bounds__(256)
void k_conv3_mfma(const bf16* __restrict__ in0, int C0,
                  const bf16* __restrict__ in1, int C1,
                  const bf16* __restrict__ wt, int Cip,
                  const unsigned char* __restrict__ mask,
                  void* __restrict__ out, long long out_off,
                  const int* __restrict__ flag, int use_flag,
                  int B, int H, int W, int Co, int cotiles){
  int lane = threadIdx.x & 63;
  int wid  = threadIdx.x >> 6;
  int n16  = lane & 15, quad = lane >> 4;
  int x0 = (blockIdx.x*4 + wid)*16;
  int y  = blockIdx.y;
  int b  = blockIdx.z / cotiles;
  int ct = blockIdx.z % cotiles;
  int co0 = ct * (16*COT);
  int Citot = C0 + C1;

  f4 acc[COT];
  #pragma unroll
  for (int j = 0; j < COT; ++j) acc[j] = (f4){0.f,0.f,0.f,0.f};

  bf8 az;
  #pragma unroll
  for (int i = 0; i < 8; ++i) az[i] = (__bf16)0.f;

  int x = x0 + n16;
  for (int dy = 0; dy < 3; ++dy){
    int yy = y + dy - 1;
    if ((unsigned)yy >= (unsigned)H) continue;
    long long rowb = ((long long)b*H + yy)*(long long)W;
    for (int dx = 0; dx < 3; ++dx){
      int xx = x + dx - 1;
      bool xok = (unsigned)xx < (unsigned)W;
      long long sb = rowb + xx;
      int tap = dy*3 + dx;
      for (int k0 = 0; k0 < Cip; k0 += 32){
        int c = k0 + quad*8;
        bf8 a = az;
        if (xok && c < Citot){
          a = (c < C0) ? *(const bf8*)(const void*)(in0 + sb*(long long)C0 + c)
                       : *(const bf8*)(const void*)(in1 + sb*(long long)C1 + (c - C0));
        }
        #pragma unroll
        for (int j = 0; j < COT; ++j){
          bf8 bfrag = *(const bf8*)(const void*)(wt + ((long long)(tap*Co + co0 + j*16 + n16))*Cip + k0 + quad*8);
          acc[j] = __builtin_amdgcn_mfma_f32_16x16x32_bf16(a, bfrag, acc[j], 0, 0, 0);
        }
      }
    }
  }

  int f = use_flag ? *flag : 0;
  long long srow = ((long long)b*H + y)*(long long)W;
  #pragma unroll
  for (int j = 0; j < COT; ++j){
    #pragma unroll
    for (int r = 0; r < 4; ++r){
      int sx = x0 + quad*4 + r;
      long long s = srow + sx;
      float v = mask[s] ? acc[j][r] : 0.f;
      long long o = out_off + s*(long long)Co + co0 + j*16 + n16;
      if (f) ((float*)out)[o] = v;
      else   ((bf16*)out)[o]  = f2b(v);
    }
  }
}

// ---------------- MFMA transpose conv 2x2 stride 2 ----------------
// One wave: 16 input sites (consecutive ix) x (16*COT) co x ALL 4 parities.
// wt layout: [4][Co][Ci] (d = di*2+dj). A-frag reused 4x.
template<int COT>
__global__ __launch_bounds__(256)
void k_tconv_mfma(const bf16* __restrict__ in, const bf16* __restrict__ wt,
                  bf16* __restrict__ out, int B, int Hi, int Wi, int Ci, int Co, int cotiles){
  int lane = threadIdx.x & 63;
  int wid  = threadIdx.x >> 6;
  int n16  = lane & 15, quad = lane >> 4;
  int ix0 = (blockIdx.x*4 + wid)*16;
  int iy  = blockIdx.y;
  int b   = blockIdx.z / cotiles;
  int ct  = blockIdx.z % cotiles;
  int co0 = ct * (16*COT);

  f4 acc[4][COT];
  #pragma unroll
  for (int d = 0; d < 4; ++d)
    #pragma unroll
    for (int j = 0; j < COT; ++j) acc[d][j] = (f4){0.f,0.f,0.f,0.f};

  const bf16* ip = in + (((long long)b*Hi + iy)*(long long)Wi + ix0 + n16)*(long long)Ci;
  for (int k0 = 0; k0 < Ci; k0 += 32){
    bf8 a = *(const bf8*)(const void*)(ip + k0 + quad*8);
    #pragma unroll
    for (int d = 0; d < 4; ++d){
      #pragma unroll
      for (int j = 0; j < COT; ++j){
        bf8 bfrag = *(const bf8*)(const void*)(wt + ((long long)(d*Co + co0 + j*16 + n16))*Ci + k0 + quad*8);
        acc[d][j] = __builtin_amdgcn_mfma_f32_16x16x32_bf16(a, bfrag, acc[d][j], 0, 0, 0);
      }
    }
  }

  int Ho = Hi*2, Wo = Wi*2;
  #pragma unroll
  for (int d = 0; d < 4; ++d){
    int di = d >> 1, dj = d & 1;
    long long rowo = ((long long)b*Ho + 2*iy + di)*(long long)Wo;
    #pragma unroll
    for (int j = 0; j < COT; ++j){
      #pragma unroll
      for (int r = 0; r < 4; ++r){
        int ix = ix0 + quad*4 + r;
        long long o = (rowo + 2*ix + dj)*(long long)Co + co0 + j*16 + n16;
        out[o] = f2b(acc[d][j][r]);
      }
    }
  }
}

// ---------------- ds1: Ci=1, Co=16, weights in LDS, thread per site ----------------
__global__ void k_ds1(const int* __restrict__ flag, const bf16* __restrict__ xm,
                      const void* __restrict__ w, const unsigned char* __restrict__ mask,
                      bf16* __restrict__ out, int B, int H, int W){
  __shared__ float ws[144];
  if (threadIdx.x < 144)
    ws[threadIdx.x] = (*flag) ? ldv<float>(w, threadIdx.x) : ldv<bf16>(w, threadIdx.x);
  __syncthreads();
  long long s = blockIdx.x*(long long)blockDim.x + threadIdx.x;
  long long total = (long long)B*H*W;
  if (s >= total) return;
  int x = (int)(s % W);
  long long t = s / W;
  int y = (int)(t % H);
  int b = (int)(t / H);
  bf8 oz[2];
  #pragma unroll
  for (int h = 0; h < 2; ++h)
    #pragma unroll
    for (int i = 0; i < 8; ++i) oz[h][i] = (__bf16)0.f;
  if (mask[s]){
    float acc[16];
    #pragma unroll
    for (int i = 0; i < 16; ++i) acc[i] = 0.f;
    for (int dy = 0; dy < 3; ++dy){
      int yy = y + dy - 1;
      if ((unsigned)yy >= (unsigned)H) continue;
      long long rowb = ((long long)b*H + yy)*(long long)W;
      for (int dx = 0; dx < 3; ++dx){
        int xx = x + dx - 1;
        if ((unsigned)xx >= (unsigned)W) continue;
        float xv = b2f(xm[rowb + xx]);
        const float* wp = ws + (dy*3 + dx)*16;
        #pragma unroll
        for (int i = 0; i < 16; ++i) acc[i] += xv * wp[i];
      }
    }
    #pragma unroll
    for (int h = 0; h < 2; ++h)
      #pragma unroll
      for (int i = 0; i < 8; ++i) oz[h][i] = (__bf16)acc[h*8+i];
  }
  bf8* op = (bf8*)(void*)(out + s*16);
  op[0] = oz[0]; op[1] = oz[1];
}

// ---------------- vectorized masked 2x2 stride-2 maxpool (8 ch / thread) ----------------
__global__ void k_pool8(const bf16* __restrict__ in, const unsigned char* __restrict__ mi,
                        bf16* __restrict__ out, unsigned char* __restrict__ mo,
                        int B, int Ho, int Wo, int C){
  int C8 = C >> 3;
  long long idx = blockIdx.x*(long long)blockDim.x + threadIdx.x;
  long long total = (long long)B*Ho*Wo*C8;
  if (idx >= total) return;
  int c8 = (int)(idx % C8);
  long long s = idx / C8;
  int x = (int)(s % Wo);
  long long t = s / Wo;
  int y = (int)(t % Ho);
  int b = (int)(t / Ho);
  int Hi = Ho*2, Wi = Wo*2;
  float best[8];
  #pragma unroll
  for (int i = 0; i < 8; ++i) best[i] = -3.4e38f;
  bool any = false;
  #pragma unroll
  for (int a = 0; a < 2; ++a){
    #pragma unroll
    for (int d = 0; d < 2; ++d){
      long long site = ((long long)b*Hi + (2*y+a))*(long long)Wi + (2*x+d);
      if (mi[site]){
        any = true;
        bf8 v = *(const bf8*)(const void*)(in + site*(long long)C + c8*8);
        #pragma unroll
        for (int i = 0; i < 8; ++i) best[i] = fmaxf(best[i], (float)v[i]);
      }
    }
  }
  bf8 o;
  #pragma unroll
  for (int i = 0; i < 8; ++i) o[i] = (__bf16)(any ? best[i] : 0.f);
  *(bf8*)(void*)(out + s*(long long)C + c8*8) = o;
  if (c8 == 0) mo[s] = (unsigned char)any;
}

// ---------------- cvt (4 elems / thread) ----------------
__global__ void k_cvt4(const int* __restrict__ flag, const void* __restrict__ src, long long src_off,
                       bf16* __restrict__ dst, long long n4){
  long long i = (blockIdx.x*(long long)blockDim.x + threadIdx.x)*4;
  if (i >= n4*4) return;
  int f = *flag;
  #pragma unroll
  for (int k = 0; k < 4; ++k){
    float v = f ? ldv<float>(src, src_off+i+k) : ldv<bf16>(src, src_off+i+k);
    dst[i+k] = f2b(v);
  }
}

// ---------------- head: 1x1 conv 16->3, thread per site ----------------
__global__ void k_head(const int* __restrict__ flag, const bf16* __restrict__ in,
                       const void* __restrict__ w, const unsigned char* __restrict__ mask,
                       void* __restrict__ out, int B, int H, int W){
  __shared__ float ws[48];
  if (threadIdx.x < 48)
    ws[threadIdx.x] = (*flag) ? ldv<float>(w, threadIdx.x) : ldv<bf16>(w, threadIdx.x);
  __syncthreads();
  long long s = blockIdx.x*(long long)blockDim.x + threadIdx.x;
  long long total = (long long)B*H*W;
  if (s >= total) return;
  float acc[3] = {0.f, 0.f, 0.f};
  if (mask[s]){
    const bf8* ip = (const bf8*)(const void*)(in + s*16);
    bf8 v0 = ip[0], v1 = ip[1];
    #pragma unroll
    for (int c = 0; c < 8; ++c){
      float a = (float)v0[c], bv = (float)v1[c];
      #pragma unroll
      for (int co = 0; co < 3; ++co){
        acc[co] += a  * ws[c*3 + co];
        acc[co] += bv * ws[(c+8)*3 + co];
      }
    }
  }
  int f = *flag;
  #pragma unroll
  for (int co = 0; co < 3; ++co){
    long long o = s*3 + co;
    if (f) ((float*)out)[o] = acc[co];
    else   ((bf16*)out)[o]  = f2b(acc[co]);
  }
}

// ---------------- host side ----------------
static inline dim3 grid1d(long long total, int block){
  return dim3((unsigned)((total + block - 1) / block));
}

extern "C" void kernel_launch(void* const* d_in, const int* in_sizes, int n_in,
                              void* d_out, int out_size, void* d_ws, size_t ws_size,
                              hipStream_t stream) {
  const void* x    = d_in[0];
  const int* mask  = (const int*)d_in[1];
  const void* w_ds1=d_in[2], *w_ds2=d_in[3], *w_ds3=d_in[4], *w_ds4=d_in[5];
  const void* w_bridge=d_in[6];
  const void* wt4=d_in[7], *w_us4=d_in[8], *wt3=d_in[9], *w_us3=d_in[10];
  const void* wt2=d_in[11], *w_us2=d_in[12], *wt1=d_in[13], *w_us1=d_in[14];
  const void* w_out=d_in[15];

  const long long C2_OFF = (long long)2*1024*1024*3;
  const int B = 2;

  int* flag = (int*)d_ws;
  bf16* wsb = (bf16*)((char*)d_ws + 16);
  long long off = 0;
  bf16* xm   = wsb + off; off += (long long)2*1024*1024*1;
  bf16* c1   = wsb + off; off += (long long)2*1024*1024*16;
  bf16* c2b  = wsb + off; off += (long long)2*512*512*32;
  bf16* c3   = wsb + off; off += (long long)2*256*256*64;
  bf16* c4   = wsb + off; off += (long long)2*128*128*128;
  bf16* ping = wsb + off; off += (long long)2*1024*1024*16;
  bf16* pong = wsb + off; off += (long long)2*1024*1024*16;
  // transposed bf16 conv3 weights [9][Co][Cip]
  bf16* wtds2 = wsb + off; off += (long long)9*32*32;
  bf16* wtds3 = wsb + off; off += (long long)9*64*32;
  bf16* wtds4 = wsb + off; off += (long long)9*128*64;
  bf16* wtbr  = wsb + off; off += (long long)9*256*128;
  bf16* wtus4 = wsb + off; off += (long long)9*128*256;
  bf16* wtus3 = wsb + off; off += (long long)9*64*128;
  bf16* wtus2 = wsb + off; off += (long long)9*32*64;
  bf16* wtus1 = wsb + off; off += (long long)9*16*32;
  // transposed bf16 tconv weights [4][Co][Ci]
  bf16* wtt4 = wsb + off; off += (long long)4*128*256;
  bf16* wtt3 = wsb + off; off += (long long)4*64*128;
  bf16* wtt2 = wsb + off; off += (long long)4*32*64;
  bf16* wtt1 = wsb + off; off += (long long)4*16*32;
  unsigned char* mb = (unsigned char*)(wsb + off);
  long long mo = 0;
  unsigned char* m0u = mb + mo; mo += (long long)2*1024*1024;
  unsigned char* m1  = mb + mo; mo += (long long)2*512*512;
  unsigned char* m2  = mb + mo; mo += (long long)2*256*256;
  unsigned char* m3  = mb + mo; mo += (long long)2*128*128;
  unsigned char* m4  = mb + mo; mo += (long long)2*64*64;
  unsigned char* mc4 = mb + mo; mo += (long long)2*128*128;
  unsigned char* mc3 = mb + mo; mo += (long long)2*256*256;
  unsigned char* mc2 = mb + mo; mo += (long long)2*512*512;
  unsigned char* mc1 = mb + mo; mo += (long long)2*1024*1024;

  const int BK = 256;
  long long n;

  // dtype detection + prep
  k_zero_flag<<<1,1,0,stream>>>(flag);
  n = (long long)B*1024*1024;
  k_detect<<<grid1d(n,BK),BK,0,stream>>>((const unsigned short*)x, n, flag);
  k_prep  <<<grid1d(n,BK),BK,0,stream>>>(x, mask, flag, xm, m0u, n);

  // conv3 weight transforms (taps=9): (Ci, Co, Cip)
  k_wt<<<grid1d((long long)9*32*32 ,BK),BK,0,stream>>>(flag, w_ds2,   wtds2, 9,  16,  32,  32);
  k_wt<<<grid1d((long long)9*64*32 ,BK),BK,0,stream>>>(flag, w_ds3,   wtds3, 9,  32,  64,  32);
  k_wt<<<grid1d((long long)9*128*64,BK),BK,0,stream>>>(flag, w_ds4,   wtds4, 9,  64, 128,  64);
  k_wt<<<grid1d((long long)9*256*128,BK),BK,0,stream>>>(flag, w_bridge,wtbr , 9, 128, 256, 128);
  k_wt<<<grid1d((long long)9*128*256,BK),BK,0,stream>>>(flag, w_us4,  wtus4, 9, 256, 128, 256);
  k_wt<<<grid1d((long long)9*64*128,BK),BK,0,stream>>>(flag, w_us3,   wtus3, 9, 128,  64, 128);
  k_wt<<<grid1d((long long)9*32*64 ,BK),BK,0,stream>>>(flag, w_us2,   wtus2, 9,  64,  32,  64);
  k_wt<<<grid1d((long long)9*16*32 ,BK),BK,0,stream>>>(flag, w_us1,   wtus1, 9,  32,  16,  32);
  // tconv weight transforms (taps=4): Cip=Ci
  k_wt<<<grid1d((long long)4*128*256,BK),BK,0,stream>>>(flag, wt4, wtt4, 4, 256, 128, 256);
  k_wt<<<grid1d((long long)4*64*128 ,BK),BK,0,stream>>>(flag, wt3, wtt3, 4, 128,  64, 128);
  k_wt<<<grid1d((long long)4*32*64  ,BK),BK,0,stream>>>(flag, wt2, wtt2, 4,  64,  32,  64);
  k_wt<<<grid1d((long long)4*16*32  ,BK),BK,0,stream>>>(flag, wt1, wtt1, 4,  32,  16,  32);

  // ds1 (Ci=1)
  n = (long long)B*1024*1024;
  k_ds1<<<grid1d(n,BK),BK,0,stream>>>(flag, xm, w_ds1, m0u, c1, B,1024,1024);
  n = (long long)B*512*512*2;   // sites * C/8 (C=16)
  k_pool8<<<grid1d(n,BK),BK,0,stream>>>(c1, m0u, ping, m1, B,512,512,16);

  // ds2 (MFMA) -> d_out (c2), then cvt to c2b
  k_conv3_mfma<2><<<dim3(512/64,512,B*1),256,0,stream>>>(ping,16, nullptr,0, wtds2,32, m1, d_out, C2_OFF, flag,1, B,512,512,32, 1);
  n = (long long)B*512*512*32;
  k_cvt4<<<grid1d(n/4,BK),BK,0,stream>>>(flag, d_out, C2_OFF, c2b, n/4);
  n = (long long)B*256*256*4;   // C=32
  k_pool8<<<grid1d(n,BK),BK,0,stream>>>(c2b, m1, ping, m2, B,256,256,32);

  // ds3
  k_conv3_mfma<2><<<dim3(256/64,256,B*2),256,0,stream>>>(ping,32, nullptr,0, wtds3,32, m2, c3, 0, flag,0, B,256,256,64, 2);
  n = (long long)B*128*128*8;   // C=64
  k_pool8<<<grid1d(n,BK),BK,0,stream>>>(c3, m2, ping, m3, B,128,128,64);

  // ds4
  k_conv3_mfma<2><<<dim3(128/64,128,B*4),256,0,stream>>>(ping,64, nullptr,0, wtds4,64, m3, c4, 0, flag,0, B,128,128,128, 4);
  n = (long long)B*64*64*16;    // C=128
  k_pool8<<<grid1d(n,BK),BK,0,stream>>>(c4, m3, ping, m4, B,64,64,128);

  // bridge
  k_conv3_mfma<2><<<dim3(64/64,64,B*8),256,0,stream>>>(ping,128, nullptr,0, wtbr,128, m4, pong, 0, flag,0, B,64,64,256, 8);

  // decoder 4
  k_tconv_mfma<2><<<dim3(64/64,64,B*4),256,0,stream>>>(pong, wtt4, ping, B,64,64,256,128, 4);
  n = (long long)B*128*128;
  k_mask_comb<<<grid1d(n,BK),BK,0,stream>>>(m4, m3, mc4, B,128,128);
  k_conv3_mfma<2><<<dim3(128/64,128,B*4),256,0,stream>>>(ping,128, c4,128, wtus4,256, mc4, pong, 0, flag,0, B,128,128,128, 4);

  // decoder 3
  k_tconv_mfma<2><<<dim3(128/64,128,B*2),256,0,stream>>>(pong, wtt3, ping, B,128,128,128,64, 2);
  n = (long long)B*256*256;
  k_mask_comb<<<grid1d(n,BK),BK,0,stream>>>(mc4, m2, mc3, B,256,256);
  k_conv3_mfma<2><<<dim3(256/64,256,B*2),256,0,stream>>>(ping,64, c3,64, wtus3,128, mc3, pong, 0, flag,0, B,256,256,64, 2);

  // decoder 2
  k_tconv_mfma<2><<<dim3(256/64,256,B*1),256,0,stream>>>(pong, wtt2, ping, B,256,256,64,32, 1);
  n = (long long)B*512*512;
  k_mask_comb<<<grid1d(n,BK),BK,0,stream>>>(mc3, m1, mc2, B,512,512);
  k_conv3_mfma<2><<<dim3(512/64,512,B*1),256,0,stream>>>(ping,32, c2b,32, wtus2,64, mc2, pong, 0, flag,0, B,512,512,32, 1);

  // decoder 1
  k_tconv_mfma<1><<<dim3(512/64,512,B*1),256,0,stream>>>(pong, wtt1, ping, B,512,512,32,16, 1);
  n = (long long)B*1024*1024;
  k_mask_comb<<<grid1d(n,BK),BK,0,stream>>>(mc2, m0u, mc1, B,1024,1024);
  k_conv3_mfma<1><<<dim3(1024/64,1024,B*1),256,0,stream>>>(ping,16, c1,16, wtus1,32, mc1, pong, 0, flag,0, B,1024,1024,16, 1);

  // head
  n = (long long)B*1024*1024;
  k_head<<<grid1d(n,BK),BK,0,stream>>>(flag, pong, w_out, mc1, d_out, B,1024,1024);
}

// Round 5
// 1248.605 us; speedup vs baseline: 11.3148x; 1.0398x over previous
//
#include <hip/hip_runtime.h>
#include <hip/hip_bf16.h>

using bf16 = __hip_bfloat16;
typedef __bf16 bf8 __attribute__((ext_vector_type(8)));
typedef float  f4  __attribute__((ext_vector_type(4)));

__device__ __forceinline__ float b2f(bf16 v){ return __bfloat162float(v); }
__device__ __forceinline__ bf16 f2b(float v){ return __float2bfloat16(v); }

template<typename T> __device__ __forceinline__ float ldv(const void* p, long long i);
template<> __device__ __forceinline__ float ldv<float>(const void* p, long long i){ return ((const float*)p)[i]; }
template<> __device__ __forceinline__ float ldv<bf16 >(const void* p, long long i){ return b2f(((const bf16*)p)[i]); }

// ---------------- dtype detection ----------------
__global__ void k_zero_flag(int* f){ *f = 0; }

__global__ void k_detect(const unsigned short* __restrict__ x, long long n, int* __restrict__ flag){
  long long i = blockIdx.x*(long long)blockDim.x + threadIdx.x;
  if (i >= n) return;
  unsigned short u = x[i];
  if ((u & 0x7F80u) == 0x7F80u) atomicOr(flag, 1);
}

// ---------------- prep ----------------
__global__ void k_prep(const void* __restrict__ x, const int* __restrict__ m, const int* __restrict__ flag,
                       bf16* __restrict__ xo, unsigned char* __restrict__ mo, long long n){
  long long i = blockIdx.x*(long long)blockDim.x + threadIdx.x;
  if (i >= n) return;
  int f = *flag;
  int mm = (m[i] != 0);
  mo[i] = (unsigned char)mm;
  float v = f ? ldv<float>(x, i) : ldv<bf16>(x, i);
  xo[i] = f2b(mm ? v : 0.f);
}

__global__ void k_mask_comb(const unsigned char* __restrict__ coarse,
                            const unsigned char* __restrict__ fine,
                            unsigned char* __restrict__ mo,
                            int B, int H, int W){
  long long i = blockIdx.x*(long long)blockDim.x + threadIdx.x;
  long long total = (long long)B*H*W;
  if (i >= total) return;
  int x = (int)(i % W);
  long long t = i / W;
  int y = (int)(t % H);
  int b = (int)(t / H);
  unsigned char c = coarse[((long long)b*(H/2) + (y>>1))*(W/2) + (x>>1)];
  mo[i] = (unsigned char)(c | fine[i]);
}

// ---------------- weight transform: [taps][Ci][Co] (flag dtype) -> bf16 [taps][Co][Cip] ----------------
__global__ void k_wt(const int* __restrict__ flag, const void* __restrict__ w, bf16* __restrict__ wt,
                     int taps, int Ci, int Co, int Cip){
  long long i = blockIdx.x*(long long)blockDim.x + threadIdx.x;
  long long total = (long long)taps*Co*Cip;
  if (i >= total) return;
  int ci = (int)(i % Cip);
  long long t2 = i / Cip;
  int co = (int)(t2 % Co);
  int tap = (int)(t2 / Co);
  float v = 0.f;
  if (ci < Ci){
    long long src = ((long long)tap*Ci + ci)*Co + co;
    v = (*flag) ? ldv<float>(w, src) : ldv<bf16>(w, src);
  }
  wt[i] = f2b(v);
}

// ---------------- MFMA implicit-GEMM conv3x3, compile-time channels ----------------
// Wave: 16 sites (consecutive x) x (16*COT) co. Per (dy,k-step): batch-load
// 3 A-frags + 3*COT B-frags (independent), then 3*COT MFMAs.
// A frag: A[m=lane&15][k=quad*8+j]; B from wt[tap][co][CIP]; D: row=quad*4+r, col=lane&15.
template<int CI0,int CI1,int CIP,int CO,int COT>
__global__ __launch_bounds__(256)
void k_conv3m(const bf16* __restrict__ in0, const bf16* __restrict__ in1,
              const bf16* __restrict__ wt, const unsigned char* __restrict__ mask,
              void* __restrict__ out, long long out_off, bf16* __restrict__ out2,
              const int* __restrict__ flag, int use_flag,
              int B, int H, int W, int cotiles){
  constexpr int KS = CIP/32;
  int lane = threadIdx.x & 63;
  int wid  = threadIdx.x >> 6;
  int n16  = lane & 15, quad = lane >> 4;
  int x0 = (blockIdx.x*4 + wid)*16;
  int y  = blockIdx.y;
  int b  = blockIdx.z / cotiles;
  int ct = blockIdx.z - b*cotiles;
  int co0 = ct * (16*COT);

  f4 acc[COT];
  #pragma unroll
  for (int j = 0; j < COT; ++j) acc[j] = (f4){0.f,0.f,0.f,0.f};
  bf8 az;
  #pragma unroll
  for (int i = 0; i < 8; ++i) az[i] = (__bf16)0.f;

  bool interior = (x0 > 0) && (x0 + 16 < W);   // wave-uniform
  int xA = x0 + n16 - 1;                        // dx=0 site x

  for (int dy = 0; dy < 3; ++dy){
    int yy = y + dy - 1;
    if ((unsigned)yy >= (unsigned)H) continue;   // block-uniform
    const bf16* r0 = in0 + ((long long)b*H + yy)*(long long)W*CI0;
    const bf16* r1 = (CI1 > 0) ? in1 + ((long long)b*H + yy)*(long long)W*CI1 : nullptr;
    const bf16* wrow = wt + ((long long)(dy*3)*CO)*CIP;
    if (interior){
      #pragma unroll
      for (int k0 = 0; k0 < KS; ++k0){
        int c = k0*32 + quad*8;
        bf8 af[3]; bf8 bv[3][COT];
        #pragma unroll
        for (int dx = 0; dx < 3; ++dx){
          long long sx = xA + dx;
          if constexpr (CI1 > 0){
            const bf16* p = (c < CI0) ? r0 + sx*CI0 + c : r1 + sx*CI1 + (c - CI0);
            af[dx] = *(const bf8*)(const void*)p;
          } else if constexpr (CIP > CI0){
            int cc = (c < CI0) ? c : 0;
            bf8 tmp = *(const bf8*)(const void*)(r0 + sx*CI0 + cc);
            af[dx] = (c < CI0) ? tmp : az;
          } else {
            af[dx] = *(const bf8*)(const void*)(r0 + sx*CI0 + c);
          }
          #pragma unroll
          for (int j = 0; j < COT; ++j)
            bv[dx][j] = *(const bf8*)(const void*)(wrow + ((long long)(dx*CO + co0 + j*16 + n16))*CIP + k0*32 + quad*8);
        }
        #pragma unroll
        for (int dx = 0; dx < 3; ++dx)
          #pragma unroll
          for (int j = 0; j < COT; ++j)
            acc[j] = __builtin_amdgcn_mfma_f32_16x16x32_bf16(af[dx], bv[dx][j], acc[j], 0, 0, 0);
      }
    } else {
      #pragma unroll
      for (int k0 = 0; k0 < KS; ++k0){
        int c = k0*32 + quad*8;
        bf8 af[3]; bf8 bv[3][COT];
        #pragma unroll
        for (int dx = 0; dx < 3; ++dx){
          int xx = xA + dx;
          bool ok = (unsigned)xx < (unsigned)W;
          long long sx = ok ? xx : 0;
          bf8 tmp;
          if constexpr (CI1 > 0){
            const bf16* p = (c < CI0) ? r0 + sx*CI0 + c : r1 + sx*CI1 + (c - CI0);
            tmp = *(const bf8*)(const void*)p;
          } else if constexpr (CIP > CI0){
            int cc = (c < CI0) ? c : 0;
            tmp = *(const bf8*)(const void*)(r0 + sx*CI0 + cc);
            if (c >= CI0) ok = false;
          } else {
            tmp = *(const bf8*)(const void*)(r0 + sx*CI0 + c);
          }
          af[dx] = ok ? tmp : az;
          #pragma unroll
          for (int j = 0; j < COT; ++j)
            bv[dx][j] = *(const bf8*)(const void*)(wrow + ((long long)(dx*CO + co0 + j*16 + n16))*CIP + k0*32 + quad*8);
        }
        #pragma unroll
        for (int dx = 0; dx < 3; ++dx)
          #pragma unroll
          for (int j = 0; j < COT; ++j)
            acc[j] = __builtin_amdgcn_mfma_f32_16x16x32_bf16(af[dx], bv[dx][j], acc[j], 0, 0, 0);
      }
    }
  }

  int f = use_flag ? *flag : 0;
  long long srow = ((long long)b*H + y)*(long long)W;
  #pragma unroll
  for (int j = 0; j < COT; ++j){
    #pragma unroll
    for (int r = 0; r < 4; ++r){
      int sx = x0 + quad*4 + r;
      long long s = srow + sx;
      float v = mask[s] ? acc[j][r] : 0.f;
      long long o = s*(long long)CO + co0 + j*16 + n16;
      if (out2) out2[o] = f2b(v);
      if (f) ((float*)out)[out_off + o] = v;
      else   ((bf16*)out)[out_off + o]  = f2b(v);
    }
  }
}

// ---------------- MFMA transpose conv 2x2 stride 2, compile-time channels ----------------
// One wave: 16 input sites x (16*COT) co x all 4 parities; A reused 4x.
// wt layout: [4][CO][CI].
template<int CI,int CO,int COT>
__global__ __launch_bounds__(256)
void k_tconvm(const bf16* __restrict__ in, const bf16* __restrict__ wt,
              bf16* __restrict__ out, int B, int Hi, int Wi, int cotiles){
  constexpr int KS = CI/32;
  int lane = threadIdx.x & 63;
  int wid  = threadIdx.x >> 6;
  int n16  = lane & 15, quad = lane >> 4;
  int ix0 = (blockIdx.x*4 + wid)*16;
  int iy  = blockIdx.y;
  int b   = blockIdx.z / cotiles;
  int ct  = blockIdx.z - b*cotiles;
  int co0 = ct * (16*COT);

  f4 acc[4][COT];
  #pragma unroll
  for (int d = 0; d < 4; ++d)
    #pragma unroll
    for (int j = 0; j < COT; ++j) acc[d][j] = (f4){0.f,0.f,0.f,0.f};

  const bf16* ip = in + (((long long)b*Hi + iy)*(long long)Wi + ix0 + n16)*(long long)CI;
  #pragma unroll
  for (int k0 = 0; k0 < KS; ++k0){
    bf8 a = *(const bf8*)(const void*)(ip + k0*32 + quad*8);
    bf8 bv[4][COT];
    #pragma unroll
    for (int d = 0; d < 4; ++d)
      #pragma unroll
      for (int j = 0; j < COT; ++j)
        bv[d][j] = *(const bf8*)(const void*)(wt + ((long long)(d*CO + co0 + j*16 + n16))*CI + k0*32 + quad*8);
    #pragma unroll
    for (int d = 0; d < 4; ++d)
      #pragma unroll
      for (int j = 0; j < COT; ++j)
        acc[d][j] = __builtin_amdgcn_mfma_f32_16x16x32_bf16(a, bv[d][j], acc[d][j], 0, 0, 0);
  }

  int Ho = Hi*2, Wo = Wi*2;
  #pragma unroll
  for (int d = 0; d < 4; ++d){
    int di = d >> 1, dj = d & 1;
    long long rowo = ((long long)b*Ho + 2*iy + di)*(long long)Wo;
    #pragma unroll
    for (int j = 0; j < COT; ++j){
      #pragma unroll
      for (int r = 0; r < 4; ++r){
        int ix = ix0 + quad*4 + r;
        long long o = (rowo + 2*ix + dj)*(long long)CO + co0 + j*16 + n16;
        out[o] = f2b(acc[d][j][r]);
      }
    }
  }
}

// ---------------- ds1: Ci=1, Co=16, weights in LDS, thread per site ----------------
__global__ void k_ds1(const int* __restrict__ flag, const bf16* __restrict__ xm,
                      const void* __restrict__ w, const unsigned char* __restrict__ mask,
                      bf16* __restrict__ out, int B, int H, int W){
  __shared__ float ws[144];
  if (threadIdx.x < 144)
    ws[threadIdx.x] = (*flag) ? ldv<float>(w, threadIdx.x) : ldv<bf16>(w, threadIdx.x);
  __syncthreads();
  long long s = blockIdx.x*(long long)blockDim.x + threadIdx.x;
  long long total = (long long)B*H*W;
  if (s >= total) return;
  int x = (int)(s % W);
  long long t = s / W;
  int y = (int)(t % H);
  int b = (int)(t / H);
  bf8 oz[2];
  #pragma unroll
  for (int h = 0; h < 2; ++h)
    #pragma unroll
    for (int i = 0; i < 8; ++i) oz[h][i] = (__bf16)0.f;
  if (mask[s]){
    float acc[16];
    #pragma unroll
    for (int i = 0; i < 16; ++i) acc[i] = 0.f;
    for (int dy = 0; dy < 3; ++dy){
      int yy = y + dy - 1;
      if ((unsigned)yy >= (unsigned)H) continue;
      long long rowb = ((long long)b*H + yy)*(long long)W;
      for (int dx = 0; dx < 3; ++dx){
        int xx = x + dx - 1;
        if ((unsigned)xx >= (unsigned)W) continue;
        float xv = b2f(xm[rowb + xx]);
        const float* wp = ws + (dy*3 + dx)*16;
        #pragma unroll
        for (int i = 0; i < 16; ++i) acc[i] += xv * wp[i];
      }
    }
    #pragma unroll
    for (int h = 0; h < 2; ++h)
      #pragma unroll
      for (int i = 0; i < 8; ++i) oz[h][i] = (__bf16)acc[h*8+i];
  }
  bf8* op = (bf8*)(void*)(out + s*16);
  op[0] = oz[0]; op[1] = oz[1];
}

// ---------------- vectorized masked 2x2 stride-2 maxpool (8 ch / thread) ----------------
__global__ void k_pool8(const bf16* __restrict__ in, const unsigned char* __restrict__ mi,
                        bf16* __restrict__ out, unsigned char* __restrict__ mo,
                        int B, int Ho, int Wo, int C){
  int C8 = C >> 3;
  long long idx = blockIdx.x*(long long)blockDim.x + threadIdx.x;
  long long total = (long long)B*Ho*Wo*C8;
  if (idx >= total) return;
  int c8 = (int)(idx % C8);
  long long s = idx / C8;
  int x = (int)(s % Wo);
  long long t = s / Wo;
  int y = (int)(t % Ho);
  int b = (int)(t / Ho);
  int Hi = Ho*2, Wi = Wo*2;
  float best[8];
  #pragma unroll
  for (int i = 0; i < 8; ++i) best[i] = -3.4e38f;
  bool any = false;
  #pragma unroll
  for (int a = 0; a < 2; ++a){
    #pragma unroll
    for (int d = 0; d < 2; ++d){
      long long site = ((long long)b*Hi + (2*y+a))*(long long)Wi + (2*x+d);
      if (mi[site]){
        any = true;
        bf8 v = *(const bf8*)(const void*)(in + site*(long long)C + c8*8);
        #pragma unroll
        for (int i = 0; i < 8; ++i) best[i] = fmaxf(best[i], (float)v[i]);
      }
    }
  }
  bf8 o;
  #pragma unroll
  for (int i = 0; i < 8; ++i) o[i] = (__bf16)(any ? best[i] : 0.f);
  *(bf8*)(void*)(out + s*(long long)C + c8*8) = o;
  if (c8 == 0) mo[s] = (unsigned char)any;
}

// ---------------- head: 1x1 conv 16->3, thread per site ----------------
__global__ void k_head(const int* __restrict__ flag, const bf16* __restrict__ in,
                       const void* __restrict__ w, const unsigned char* __restrict__ mask,
                       void* __restrict__ out, int B, int H, int W){
  __shared__ float ws[48];
  if (threadIdx.x < 48)
    ws[threadIdx.x] = (*flag) ? ldv<float>(w, threadIdx.x) : ldv<bf16>(w, threadIdx.x);
  __syncthreads();
  long long s = blockIdx.x*(long long)blockDim.x + threadIdx.x;
  long long total = (long long)B*H*W;
  if (s >= total) return;
  float acc[3] = {0.f, 0.f, 0.f};
  if (mask[s]){
    const bf8* ip = (const bf8*)(const void*)(in + s*16);
    bf8 v0 = ip[0], v1 = ip[1];
    #pragma unroll
    for (int c = 0; c < 8; ++c){
      float a = (float)v0[c], bv = (float)v1[c];
      #pragma unroll
      for (int co = 0; co < 3; ++co){
        acc[co] += a  * ws[c*3 + co];
        acc[co] += bv * ws[(c+8)*3 + co];
      }
    }
  }
  int f = *flag;
  #pragma unroll
  for (int co = 0; co < 3; ++co){
    long long o = s*3 + co;
    if (f) ((float*)out)[o] = acc[co];
    else   ((bf16*)out)[o]  = f2b(acc[co]);
  }
}

// ---------------- host side ----------------
static inline dim3 grid1d(long long total, int block){
  return dim3((unsigned)((total + block - 1) / block));
}

extern "C" void kernel_launch(void* const* d_in, const int* in_sizes, int n_in,
                              void* d_out, int out_size, void* d_ws, size_t ws_size,
                              hipStream_t stream) {
  const void* x    = d_in[0];
  const int* mask  = (const int*)d_in[1];
  const void* w_ds1=d_in[2], *w_ds2=d_in[3], *w_ds3=d_in[4], *w_ds4=d_in[5];
  const void* w_bridge=d_in[6];
  const void* wt4=d_in[7], *w_us4=d_in[8], *wt3=d_in[9], *w_us3=d_in[10];
  const void* wt2=d_in[11], *w_us2=d_in[12], *wt1=d_in[13], *w_us1=d_in[14];
  const void* w_out=d_in[15];

  const long long C2_OFF = (long long)2*1024*1024*3;
  const int B = 2;

  int* flag = (int*)d_ws;
  bf16* wsb = (bf16*)((char*)d_ws + 16);
  long long off = 0;
  bf16* xm   = wsb + off; off += (long long)2*1024*1024*1;
  bf16* c1   = wsb + off; off += (long long)2*1024*1024*16;
  bf16* c2b  = wsb + off; off += (long long)2*512*512*32;
  bf16* c3   = wsb + off; off += (long long)2*256*256*64;
  bf16* c4   = wsb + off; off += (long long)2*128*128*128;
  bf16* ping = wsb + off; off += (long long)2*1024*1024*16;
  bf16* pong = wsb + off; off += (long long)2*1024*1024*16;
  // transposed bf16 conv3 weights [9][Co][Cip]
  bf16* wtds2 = wsb + off; off += (long long)9*32*32;
  bf16* wtds3 = wsb + off; off += (long long)9*64*32;
  bf16* wtds4 = wsb + off; off += (long long)9*128*64;
  bf16* wtbr  = wsb + off; off += (long long)9*256*128;
  bf16* wtus4 = wsb + off; off += (long long)9*128*256;
  bf16* wtus3 = wsb + off; off += (long long)9*64*128;
  bf16* wtus2 = wsb + off; off += (long long)9*32*64;
  bf16* wtus1 = wsb + off; off += (long long)9*16*32;
  // transposed bf16 tconv weights [4][Co][Ci]
  bf16* wtt4 = wsb + off; off += (long long)4*128*256;
  bf16* wtt3 = wsb + off; off += (long long)4*64*128;
  bf16* wtt2 = wsb + off; off += (long long)4*32*64;
  bf16* wtt1 = wsb + off; off += (long long)4*16*32;
  unsigned char* mb = (unsigned char*)(wsb + off);
  long long mo = 0;
  unsigned char* m0u = mb + mo; mo += (long long)2*1024*1024;
  unsigned char* m1  = mb + mo; mo += (long long)2*512*512;
  unsigned char* m2  = mb + mo; mo += (long long)2*256*256;
  unsigned char* m3  = mb + mo; mo += (long long)2*128*128;
  unsigned char* m4  = mb + mo; mo += (long long)2*64*64;
  unsigned char* mc4 = mb + mo; mo += (long long)2*128*128;
  unsigned char* mc3 = mb + mo; mo += (long long)2*256*256;
  unsigned char* mc2 = mb + mo; mo += (long long)2*512*512;
  unsigned char* mc1 = mb + mo; mo += (long long)2*1024*1024;

  const int BK = 256;
  long long n;

  // dtype detection + prep
  k_zero_flag<<<1,1,0,stream>>>(flag);
  n = (long long)B*1024*1024;
  k_detect<<<grid1d(n,BK),BK,0,stream>>>((const unsigned short*)x, n, flag);
  k_prep  <<<grid1d(n,BK),BK,0,stream>>>(x, mask, flag, xm, m0u, n);

  // conv3 weight transforms (taps=9): (Ci, Co, Cip)
  k_wt<<<grid1d((long long)9*32*32 ,BK),BK,0,stream>>>(flag, w_ds2,   wtds2, 9,  16,  32,  32);
  k_wt<<<grid1d((long long)9*64*32 ,BK),BK,0,stream>>>(flag, w_ds3,   wtds3, 9,  32,  64,  32);
  k_wt<<<grid1d((long long)9*128*64,BK),BK,0,stream>>>(flag, w_ds4,   wtds4, 9,  64, 128,  64);
  k_wt<<<grid1d((long long)9*256*128,BK),BK,0,stream>>>(flag, w_bridge,wtbr , 9, 128, 256, 128);
  k_wt<<<grid1d((long long)9*128*256,BK),BK,0,stream>>>(flag, w_us4,  wtus4, 9, 256, 128, 256);
  k_wt<<<grid1d((long long)9*64*128,BK),BK,0,stream>>>(flag, w_us3,   wtus3, 9, 128,  64, 128);
  k_wt<<<grid1d((long long)9*32*64 ,BK),BK,0,stream>>>(flag, w_us2,   wtus2, 9,  64,  32,  64);
  k_wt<<<grid1d((long long)9*16*32 ,BK),BK,0,stream>>>(flag, w_us1,   wtus1, 9,  32,  16,  32);
  // tconv weight transforms (taps=4): Cip=Ci
  k_wt<<<grid1d((long long)4*128*256,BK),BK,0,stream>>>(flag, wt4, wtt4, 4, 256, 128, 256);
  k_wt<<<grid1d((long long)4*64*128 ,BK),BK,0,stream>>>(flag, wt3, wtt3, 4, 128,  64, 128);
  k_wt<<<grid1d((long long)4*32*64  ,BK),BK,0,stream>>>(flag, wt2, wtt2, 4,  64,  32,  64);
  k_wt<<<grid1d((long long)4*16*32  ,BK),BK,0,stream>>>(flag, wt1, wtt1, 4,  32,  16,  32);

  // ds1 (Ci=1)
  n = (long long)B*1024*1024;
  k_ds1<<<grid1d(n,BK),BK,0,stream>>>(flag, xm, w_ds1, m0u, c1, B,1024,1024);
  n = (long long)B*512*512*2;
  k_pool8<<<grid1d(n,BK),BK,0,stream>>>(c1, m0u, ping, m1, B,512,512,16);

  // ds2 (MFMA) -> d_out (c2, flag dtype) + c2b (bf16) in one pass
  k_conv3m<16,0,32,32,2><<<dim3(8,512,2),256,0,stream>>>(ping,nullptr, wtds2, m1, d_out, C2_OFF, c2b, flag,1, B,512,512, 1);
  n = (long long)B*256*256*4;
  k_pool8<<<grid1d(n,BK),BK,0,stream>>>(c2b, m1, ping, m2, B,256,256,32);

  // ds3
  k_conv3m<32,0,32,64,2><<<dim3(4,256,4),256,0,stream>>>(ping,nullptr, wtds3, m2, c3, 0, nullptr, flag,0, B,256,256, 2);
  n = (long long)B*128*128*8;
  k_pool8<<<grid1d(n,BK),BK,0,stream>>>(c3, m2, ping, m3, B,128,128,64);

  // ds4
  k_conv3m<64,0,64,128,2><<<dim3(2,128,8),256,0,stream>>>(ping,nullptr, wtds4, m3, c4, 0, nullptr, flag,0, B,128,128, 4);
  n = (long long)B*64*64*16;
  k_pool8<<<grid1d(n,BK),BK,0,stream>>>(c4, m3, ping, m4, B,64,64,128);

  // bridge
  k_conv3m<128,0,128,256,2><<<dim3(1,64,16),256,0,stream>>>(ping,nullptr, wtbr, m4, pong, 0, nullptr, flag,0, B,64,64, 8);

  // decoder 4
  k_tconvm<256,128,2><<<dim3(1,64,8),256,0,stream>>>(pong, wtt4, ping, B,64,64, 4);
  n = (long long)B*128*128;
  k_mask_comb<<<grid1d(n,BK),BK,0,stream>>>(m4, m3, mc4, B,128,128);
  k_conv3m<128,128,256,128,2><<<dim3(2,128,8),256,0,stream>>>(ping,c4, wtus4, mc4, pong, 0, nullptr, flag,0, B,128,128, 4);

  // decoder 3
  k_tconvm<128,64,2><<<dim3(2,128,4),256,0,stream>>>(pong, wtt3, ping, B,128,128, 2);
  n = (long long)B*256*256;
  k_mask_comb<<<grid1d(n,BK),BK,0,stream>>>(mc4, m2, mc3, B,256,256);
  k_conv3m<64,64,128,64,2><<<dim3(4,256,4),256,0,stream>>>(ping,c3, wtus3, mc3, pong, 0, nullptr, flag,0, B,256,256, 2);

  // decoder 2
  k_tconvm<64,32,2><<<dim3(4,256,2),256,0,stream>>>(pong, wtt2, ping, B,256,256, 1);
  n = (long long)B*512*512;
  k_mask_comb<<<grid1d(n,BK),BK,0,stream>>>(mc3, m1, mc2, B,512,512);
  k_conv3m<32,32,64,32,2><<<dim3(8,512,2),256,0,stream>>>(ping,c2b, wtus2, mc2, pong, 0, nullptr, flag,0, B,512,512, 1);

  // decoder 1
  k_tconvm<32,16,1><<<dim3(8,512,2),256,0,stream>>>(pong, wtt1, ping, B,512,512, 1);
  n = (long long)B*1024*1024;
  k_mask_comb<<<grid1d(n,BK),BK,0,stream>>>(mc2, m0u, mc1, B,1024,1024);
  k_conv3m<16,16,32,16,1><<<dim3(16,1024,2),256,0,stream>>>(ping,c1, wtus1, mc1, pong, 0, nullptr, flag,0, B,1024,1024, 1);

  // head
  n = (long long)B*1024*1024;
  k_head<<<grid1d(n,BK),BK,0,stream>>>(flag, pong, w_out, mc1, d_out, B,1024,1024);
}

// Round 6
// 1095.471 us; speedup vs baseline: 12.8964x; 1.1398x over previous
//
#include <hip/hip_runtime.h>
#include <hip/hip_bf16.h>

using bf16 = __hip_bfloat16;
typedef __bf16 bf8 __attribute__((ext_vector_type(8)));
typedef float  f4  __attribute__((ext_vector_type(4)));

__device__ __forceinline__ float b2f(bf16 v){ return __bfloat162float(v); }
__device__ __forceinline__ bf16 f2b(float v){ return __float2bfloat16(v); }

template<typename T> __device__ __forceinline__ float ldv(const void* p, long long i);
template<> __device__ __forceinline__ float ldv<float>(const void* p, long long i){ return ((const float*)p)[i]; }
template<> __device__ __forceinline__ float ldv<bf16 >(const void* p, long long i){ return b2f(((const bf16*)p)[i]); }

// ---------------- dtype detection ----------------
__global__ void k_zero_flag(int* f){ *f = 0; }

__global__ void k_detect(const unsigned short* __restrict__ x, long long n, int* __restrict__ flag){
  long long i = blockIdx.x*(long long)blockDim.x + threadIdx.x;
  if (i >= n) return;
  unsigned short u = x[i];
  if ((u & 0x7F80u) == 0x7F80u) atomicOr(flag, 1);
}

// ---------------- prep ----------------
__global__ void k_prep(const void* __restrict__ x, const int* __restrict__ m, const int* __restrict__ flag,
                       bf16* __restrict__ xo, unsigned char* __restrict__ mo, long long n){
  long long i = blockIdx.x*(long long)blockDim.x + threadIdx.x;
  if (i >= n) return;
  int f = *flag;
  int mm = (m[i] != 0);
  mo[i] = (unsigned char)mm;
  float v = f ? ldv<float>(x, i) : ldv<bf16>(x, i);
  xo[i] = f2b(mm ? v : 0.f);
}

__global__ void k_mask_comb(const unsigned char* __restrict__ coarse,
                            const unsigned char* __restrict__ fine,
                            unsigned char* __restrict__ mo,
                            int B, int H, int W){
  long long i = blockIdx.x*(long long)blockDim.x + threadIdx.x;
  long long total = (long long)B*H*W;
  if (i >= total) return;
  int x = (int)(i % W);
  long long t = i / W;
  int y = (int)(t % H);
  int b = (int)(t / H);
  unsigned char c = coarse[((long long)b*(H/2) + (y>>1))*(W/2) + (x>>1)];
  mo[i] = (unsigned char)(c | fine[i]);
}

// ---------------- weight transform: [taps][Ci][Co] (flag dtype) -> bf16 [taps][Co][Cip] ----------------
__global__ void k_wt(const int* __restrict__ flag, const void* __restrict__ w, bf16* __restrict__ wt,
                     int taps, int Ci, int Co, int Cip){
  long long i = blockIdx.x*(long long)blockDim.x + threadIdx.x;
  long long total = (long long)taps*Co*Cip;
  if (i >= total) return;
  int ci = (int)(i % Cip);
  long long t2 = i / Cip;
  int co = (int)(t2 % Co);
  int tap = (int)(t2 / Co);
  float v = 0.f;
  if (ci < Ci){
    long long src = ((long long)tap*Ci + ci)*Co + co;
    v = (*flag) ? ldv<float>(w, src) : ldv<bf16>(w, src);
  }
  wt[i] = f2b(v);
}

// ---------------- MFMA implicit-GEMM conv3x3 ----------------
// Wave: 16 sites (x) x ROWS rows x (16*COT) co. Per k-step: batch-load
// (ROWS+2)*3 A-frags (row-clamped, cndmask-zeroed) + 9*COT B-frags, then
// ROWS*9*COT MFMAs. A[m=lane&15][k=quad*8+j]; D: row=quad*4+r, col=lane&15.
template<int CI0,int CI1,int CIP,int CO,int COT,int ROWS>
__global__ __launch_bounds__(256)
void k_conv3m(const bf16* __restrict__ in0, const bf16* __restrict__ in1,
              const bf16* __restrict__ wt, const unsigned char* __restrict__ mask,
              void* __restrict__ out, long long out_off, bf16* __restrict__ out2,
              const int* __restrict__ flag, int use_flag,
              int B, int H, int W, int cotiles){
  constexpr int KS = CIP/32;
  constexpr int NR = ROWS + 2;
  int lane = threadIdx.x & 63;
  int wid  = threadIdx.x >> 6;
  int n16  = lane & 15, quad = lane >> 4;
  int x0 = (blockIdx.x*4 + wid)*16;
  int y0 = blockIdx.y*ROWS;
  int b  = blockIdx.z / cotiles;
  int ct = blockIdx.z - b*cotiles;
  int co0 = ct * (16*COT);

  f4 acc[ROWS][COT];
  #pragma unroll
  for (int r = 0; r < ROWS; ++r)
    #pragma unroll
    for (int j = 0; j < COT; ++j) acc[r][j] = (f4){0.f,0.f,0.f,0.f};
  bf8 az;
  #pragma unroll
  for (int i = 0; i < 8; ++i) az[i] = (__bf16)0.f;

  int xA = x0 + n16 - 1;
  const bf16* bb0 = in0 + (long long)b*H*(long long)W*CI0;
  const bf16* bb1 = (CI1 > 0) ? in1 + (long long)b*H*(long long)W*CI1 : nullptr;

  #pragma unroll
  for (int k0 = 0; k0 < KS; ++k0){
    int c = k0*32 + quad*8;
    // ---- A batch: rows y0-1 .. y0+ROWS, dx 0..2 ----
    bf8 af[NR][3];
    #pragma unroll
    for (int ir = 0; ir < NR; ++ir){
      int yy = y0 + ir - 1;
      bool yok = (unsigned)yy < (unsigned)H;
      long long rbase = (long long)(yok ? yy : 0) * W;
      #pragma unroll
      for (int dx = 0; dx < 3; ++dx){
        int xx = xA + dx;
        bool xok = (unsigned)xx < (unsigned)W;
        long long sx = rbase + (xok ? xx : 0);
        bool ok = yok && xok;
        bf8 tmp;
        if constexpr (CI1 > 0){
          const bf16* p = (c < CI0) ? bb0 + sx*CI0 + c : bb1 + sx*CI1 + (c - CI0);
          tmp = *(const bf8*)(const void*)p;
        } else if constexpr (CIP > CI0){
          int cc = (c < CI0) ? c : 0;
          tmp = *(const bf8*)(const void*)(bb0 + sx*CI0 + cc);
          if (c >= CI0) ok = false;
        } else {
          tmp = *(const bf8*)(const void*)(bb0 + sx*CI0 + c);
        }
        af[ir][dx] = ok ? tmp : az;
      }
    }
    // ---- B batch: 9 taps x COT ----
    bf8 bv[9][COT];
    #pragma unroll
    for (int t = 0; t < 9; ++t)
      #pragma unroll
      for (int j = 0; j < COT; ++j)
        bv[t][j] = *(const bf8*)(const void*)(wt + ((long long)(t*CO + co0 + j*16 + n16))*CIP + k0*32 + quad*8);
    // ---- MFMAs ----
    #pragma unroll
    for (int r = 0; r < ROWS; ++r)
      #pragma unroll
      for (int dy = 0; dy < 3; ++dy)
        #pragma unroll
        for (int dx = 0; dx < 3; ++dx)
          #pragma unroll
          for (int j = 0; j < COT; ++j)
            acc[r][j] = __builtin_amdgcn_mfma_f32_16x16x32_bf16(af[r+dy][dx], bv[dy*3+dx][j], acc[r][j], 0, 0, 0);
  }

  int f = use_flag ? *flag : 0;
  #pragma unroll
  for (int r2 = 0; r2 < ROWS; ++r2){
    long long srow = ((long long)b*H + y0 + r2)*(long long)W;
    #pragma unroll
    for (int j = 0; j < COT; ++j){
      #pragma unroll
      for (int r = 0; r < 4; ++r){
        int sx = x0 + quad*4 + r;
        long long s = srow + sx;
        float v = mask[s] ? acc[r2][j][r] : 0.f;
        long long o = s*(long long)CO + co0 + j*16 + n16;
        if (out2) out2[o] = f2b(v);
        if (f) ((float*)out)[out_off + o] = v;
        else   ((bf16*)out)[out_off + o]  = f2b(v);
      }
    }
  }
}

// ---------------- MFMA transpose conv 2x2 stride 2 ----------------
// One wave: 16 input sites x (16*COT) co x all 4 parities; A reused 4x.
// wt layout: [4][CO][CI].
template<int CI,int CO,int COT>
__global__ __launch_bounds__(256)
void k_tconvm(const bf16* __restrict__ in, const bf16* __restrict__ wt,
              bf16* __restrict__ out, int B, int Hi, int Wi, int cotiles){
  constexpr int KS = CI/32;
  int lane = threadIdx.x & 63;
  int wid  = threadIdx.x >> 6;
  int n16  = lane & 15, quad = lane >> 4;
  int ix0 = (blockIdx.x*4 + wid)*16;
  int iy  = blockIdx.y;
  int b   = blockIdx.z / cotiles;
  int ct  = blockIdx.z - b*cotiles;
  int co0 = ct * (16*COT);

  f4 acc[4][COT];
  #pragma unroll
  for (int d = 0; d < 4; ++d)
    #pragma unroll
    for (int j = 0; j < COT; ++j) acc[d][j] = (f4){0.f,0.f,0.f,0.f};

  const bf16* ip = in + (((long long)b*Hi + iy)*(long long)Wi + ix0 + n16)*(long long)CI;
  #pragma unroll
  for (int k0 = 0; k0 < KS; ++k0){
    bf8 a = *(const bf8*)(const void*)(ip + k0*32 + quad*8);
    bf8 bv[4][COT];
    #pragma unroll
    for (int d = 0; d < 4; ++d)
      #pragma unroll
      for (int j = 0; j < COT; ++j)
        bv[d][j] = *(const bf8*)(const void*)(wt + ((long long)(d*CO + co0 + j*16 + n16))*CI + k0*32 + quad*8);
    #pragma unroll
    for (int d = 0; d < 4; ++d)
      #pragma unroll
      for (int j = 0; j < COT; ++j)
        acc[d][j] = __builtin_amdgcn_mfma_f32_16x16x32_bf16(a, bv[d][j], acc[d][j], 0, 0, 0);
  }

  int Ho = Hi*2, Wo = Wi*2;
  #pragma unroll
  for (int d = 0; d < 4; ++d){
    int di = d >> 1, dj = d & 1;
    long long rowo = ((long long)b*Ho + 2*iy + di)*(long long)Wo;
    #pragma unroll
    for (int j = 0; j < COT; ++j){
      #pragma unroll
      for (int r = 0; r < 4; ++r){
        int ix = ix0 + quad*4 + r;
        long long o = (rowo + 2*ix + dj)*(long long)CO + co0 + j*16 + n16;
        out[o] = f2b(acc[d][j][r]);
      }
    }
  }
}

// ---------------- ds1: Ci=1, Co=16, weights in LDS, thread per site ----------------
__global__ void k_ds1(const int* __restrict__ flag, const bf16* __restrict__ xm,
                      const void* __restrict__ w, const unsigned char* __restrict__ mask,
                      bf16* __restrict__ out, int B, int H, int W){
  __shared__ float ws[144];
  if (threadIdx.x < 144)
    ws[threadIdx.x] = (*flag) ? ldv<float>(w, threadIdx.x) : ldv<bf16>(w, threadIdx.x);
  __syncthreads();
  long long s = blockIdx.x*(long long)blockDim.x + threadIdx.x;
  long long total = (long long)B*H*W;
  if (s >= total) return;
  int x = (int)(s % W);
  long long t = s / W;
  int y = (int)(t % H);
  int b = (int)(t / H);
  bf8 oz[2];
  #pragma unroll
  for (int h = 0; h < 2; ++h)
    #pragma unroll
    for (int i = 0; i < 8; ++i) oz[h][i] = (__bf16)0.f;
  if (mask[s]){
    float acc[16];
    #pragma unroll
    for (int i = 0; i < 16; ++i) acc[i] = 0.f;
    for (int dy = 0; dy < 3; ++dy){
      int yy = y + dy - 1;
      if ((unsigned)yy >= (unsigned)H) continue;
      long long rowb = ((long long)b*H + yy)*(long long)W;
      for (int dx = 0; dx < 3; ++dx){
        int xx = x + dx - 1;
        if ((unsigned)xx >= (unsigned)W) continue;
        float xv = b2f(xm[rowb + xx]);
        const float* wp = ws + (dy*3 + dx)*16;
        #pragma unroll
        for (int i = 0; i < 16; ++i) acc[i] += xv * wp[i];
      }
    }
    #pragma unroll
    for (int h = 0; h < 2; ++h)
      #pragma unroll
      for (int i = 0; i < 8; ++i) oz[h][i] = (__bf16)acc[h*8+i];
  }
  bf8* op = (bf8*)(void*)(out + s*16);
  op[0] = oz[0]; op[1] = oz[1];
}

// ---------------- vectorized masked 2x2 stride-2 maxpool (8 ch / thread) ----------------
__global__ void k_pool8(const bf16* __restrict__ in, const unsigned char* __restrict__ mi,
                        bf16* __restrict__ out, unsigned char* __restrict__ mo,
                        int B, int Ho, int Wo, int C){
  int C8 = C >> 3;
  long long idx = blockIdx.x*(long long)blockDim.x + threadIdx.x;
  long long total = (long long)B*Ho*Wo*C8;
  if (idx >= total) return;
  int c8 = (int)(idx % C8);
  long long s = idx / C8;
  int x = (int)(s % Wo);
  long long t = s / Wo;
  int y = (int)(t % Ho);
  int b = (int)(t / Ho);
  int Hi = Ho*2, Wi = Wo*2;
  float best[8];
  #pragma unroll
  for (int i = 0; i < 8; ++i) best[i] = -3.4e38f;
  bool any = false;
  #pragma unroll
  for (int a = 0; a < 2; ++a){
    #pragma unroll
    for (int d = 0; d < 2; ++d){
      long long site = ((long long)b*Hi + (2*y+a))*(long long)Wi + (2*x+d);
      if (mi[site]){
        any = true;
        bf8 v = *(const bf8*)(const void*)(in + site*(long long)C + c8*8);
        #pragma unroll
        for (int i = 0; i < 8; ++i) best[i] = fmaxf(best[i], (float)v[i]);
      }
    }
  }
  bf8 o;
  #pragma unroll
  for (int i = 0; i < 8; ++i) o[i] = (__bf16)(any ? best[i] : 0.f);
  *(bf8*)(void*)(out + s*(long long)C + c8*8) = o;
  if (c8 == 0) mo[s] = (unsigned char)any;
}

// ---------------- head: 1x1 conv 16->3, thread per site ----------------
__global__ void k_head(const int* __restrict__ flag, const bf16* __restrict__ in,
                       const void* __restrict__ w, const unsigned char* __restrict__ mask,
                       void* __restrict__ out, int B, int H, int W){
  __shared__ float ws[48];
  if (threadIdx.x < 48)
    ws[threadIdx.x] = (*flag) ? ldv<float>(w, threadIdx.x) : ldv<bf16>(w, threadIdx.x);
  __syncthreads();
  long long s = blockIdx.x*(long long)blockDim.x + threadIdx.x;
  long long total = (long long)B*H*W;
  if (s >= total) return;
  float acc[3] = {0.f, 0.f, 0.f};
  if (mask[s]){
    const bf8* ip = (const bf8*)(const void*)(in + s*16);
    bf8 v0 = ip[0], v1 = ip[1];
    #pragma unroll
    for (int c = 0; c < 8; ++c){
      float a = (float)v0[c], bv = (float)v1[c];
      #pragma unroll
      for (int co = 0; co < 3; ++co){
        acc[co] += a  * ws[c*3 + co];
        acc[co] += bv * ws[(c+8)*3 + co];
      }
    }
  }
  int f = *flag;
  #pragma unroll
  for (int co = 0; co < 3; ++co){
    long long o = s*3 + co;
    if (f) ((float*)out)[o] = acc[co];
    else   ((bf16*)out)[o]  = f2b(acc[co]);
  }
}

// ---------------- host side ----------------
static inline dim3 grid1d(long long total, int block){
  return dim3((unsigned)((total + block - 1) / block));
}

extern "C" void kernel_launch(void* const* d_in, const int* in_sizes, int n_in,
                              void* d_out, int out_size, void* d_ws, size_t ws_size,
                              hipStream_t stream) {
  const void* x    = d_in[0];
  const int* mask  = (const int*)d_in[1];
  const void* w_ds1=d_in[2], *w_ds2=d_in[3], *w_ds3=d_in[4], *w_ds4=d_in[5];
  const void* w_bridge=d_in[6];
  const void* wt4=d_in[7], *w_us4=d_in[8], *wt3=d_in[9], *w_us3=d_in[10];
  const void* wt2=d_in[11], *w_us2=d_in[12], *wt1=d_in[13], *w_us1=d_in[14];
  const void* w_out=d_in[15];

  const long long C2_OFF = (long long)2*1024*1024*3;
  const int B = 2;

  int* flag = (int*)d_ws;
  bf16* wsb = (bf16*)((char*)d_ws + 16);
  long long off = 0;
  bf16* xm   = wsb + off; off += (long long)2*1024*1024*1;
  bf16* c1   = wsb + off; off += (long long)2*1024*1024*16;
  bf16* c2b  = wsb + off; off += (long long)2*512*512*32;
  bf16* c3   = wsb + off; off += (long long)2*256*256*64;
  bf16* c4   = wsb + off; off += (long long)2*128*128*128;
  bf16* ping = wsb + off; off += (long long)2*1024*1024*16;
  bf16* pong = wsb + off; off += (long long)2*1024*1024*16;
  // transposed bf16 conv3 weights [9][Co][Cip]
  bf16* wtds2 = wsb + off; off += (long long)9*32*32;
  bf16* wtds3 = wsb + off; off += (long long)9*64*32;
  bf16* wtds4 = wsb + off; off += (long long)9*128*64;
  bf16* wtbr  = wsb + off; off += (long long)9*256*128;
  bf16* wtus4 = wsb + off; off += (long long)9*128*256;
  bf16* wtus3 = wsb + off; off += (long long)9*64*128;
  bf16* wtus2 = wsb + off; off += (long long)9*32*64;
  bf16* wtus1 = wsb + off; off += (long long)9*16*32;
  // transposed bf16 tconv weights [4][Co][Ci]
  bf16* wtt4 = wsb + off; off += (long long)4*128*256;
  bf16* wtt3 = wsb + off; off += (long long)4*64*128;
  bf16* wtt2 = wsb + off; off += (long long)4*32*64;
  bf16* wtt1 = wsb + off; off += (long long)4*16*32;
  unsigned char* mb = (unsigned char*)(wsb + off);
  long long mo = 0;
  unsigned char* m0u = mb + mo; mo += (long long)2*1024*1024;
  unsigned char* m1  = mb + mo; mo += (long long)2*512*512;
  unsigned char* m2  = mb + mo; mo += (long long)2*256*256;
  unsigned char* m3  = mb + mo; mo += (long long)2*128*128;
  unsigned char* m4  = mb + mo; mo += (long long)2*64*64;
  unsigned char* mc4 = mb + mo; mo += (long long)2*128*128;
  unsigned char* mc3 = mb + mo; mo += (long long)2*256*256;
  unsigned char* mc2 = mb + mo; mo += (long long)2*512*512;
  unsigned char* mc1 = mb + mo; mo += (long long)2*1024*1024;

  const int BK = 256;
  long long n;

  // dtype detection + prep
  k_zero_flag<<<1,1,0,stream>>>(flag);
  n = (long long)B*1024*1024;
  k_detect<<<grid1d(n,BK),BK,0,stream>>>((const unsigned short*)x, n, flag);
  k_prep  <<<grid1d(n,BK),BK,0,stream>>>(x, mask, flag, xm, m0u, n);

  // conv3 weight transforms (taps=9): (Ci, Co, Cip)
  k_wt<<<grid1d((long long)9*32*32 ,BK),BK,0,stream>>>(flag, w_ds2,   wtds2, 9,  16,  32,  32);
  k_wt<<<grid1d((long long)9*64*32 ,BK),BK,0,stream>>>(flag, w_ds3,   wtds3, 9,  32,  64,  32);
  k_wt<<<grid1d((long long)9*128*64,BK),BK,0,stream>>>(flag, w_ds4,   wtds4, 9,  64, 128,  64);
  k_wt<<<grid1d((long long)9*256*128,BK),BK,0,stream>>>(flag, w_bridge,wtbr , 9, 128, 256, 128);
  k_wt<<<grid1d((long long)9*128*256,BK),BK,0,stream>>>(flag, w_us4,  wtus4, 9, 256, 128, 256);
  k_wt<<<grid1d((long long)9*64*128,BK),BK,0,stream>>>(flag, w_us3,   wtus3, 9, 128,  64, 128);
  k_wt<<<grid1d((long long)9*32*64 ,BK),BK,0,stream>>>(flag, w_us2,   wtus2, 9,  64,  32,  64);
  k_wt<<<grid1d((long long)9*16*32 ,BK),BK,0,stream>>>(flag, w_us1,   wtus1, 9,  32,  16,  32);
  // tconv weight transforms (taps=4): Cip=Ci
  k_wt<<<grid1d((long long)4*128*256,BK),BK,0,stream>>>(flag, wt4, wtt4, 4, 256, 128, 256);
  k_wt<<<grid1d((long long)4*64*128 ,BK),BK,0,stream>>>(flag, wt3, wtt3, 4, 128,  64, 128);
  k_wt<<<grid1d((long long)4*32*64  ,BK),BK,0,stream>>>(flag, wt2, wtt2, 4,  64,  32,  64);
  k_wt<<<grid1d((long long)4*16*32  ,BK),BK,0,stream>>>(flag, wt1, wtt1, 4,  32,  16,  32);

  // ds1 (Ci=1)
  n = (long long)B*1024*1024;
  k_ds1<<<grid1d(n,BK),BK,0,stream>>>(flag, xm, w_ds1, m0u, c1, B,1024,1024);
  n = (long long)B*512*512*2;
  k_pool8<<<grid1d(n,BK),BK,0,stream>>>(c1, m0u, ping, m1, B,512,512,16);

  // ds2 (MFMA) -> d_out (c2, flag dtype) + c2b (bf16) in one pass
  k_conv3m<16,0,32,32,2,2><<<dim3(8,256,2),256,0,stream>>>(ping,nullptr, wtds2, m1, d_out, C2_OFF, c2b, flag,1, B,512,512, 1);
  n = (long long)B*256*256*4;
  k_pool8<<<grid1d(n,BK),BK,0,stream>>>(c2b, m1, ping, m2, B,256,256,32);

  // ds3
  k_conv3m<32,0,32,64,2,2><<<dim3(4,128,4),256,0,stream>>>(ping,nullptr, wtds3, m2, c3, 0, nullptr, flag,0, B,256,256, 2);
  n = (long long)B*128*128*8;
  k_pool8<<<grid1d(n,BK),BK,0,stream>>>(c3, m2, ping, m3, B,128,128,64);

  // ds4
  k_conv3m<64,0,64,128,2,2><<<dim3(2,64,8),256,0,stream>>>(ping,nullptr, wtds4, m3, c4, 0, nullptr, flag,0, B,128,128, 4);
  n = (long long)B*64*64*16;
  k_pool8<<<grid1d(n,BK),BK,0,stream>>>(c4, m3, ping, m4, B,64,64,128);

  // bridge
  k_conv3m<128,0,128,256,2,1><<<dim3(1,64,16),256,0,stream>>>(ping,nullptr, wtbr, m4, pong, 0, nullptr, flag,0, B,64,64, 8);

  // decoder 4
  k_tconvm<256,128,2><<<dim3(1,64,8),256,0,stream>>>(pong, wtt4, ping, B,64,64, 4);
  n = (long long)B*128*128;
  k_mask_comb<<<grid1d(n,BK),BK,0,stream>>>(m4, m3, mc4, B,128,128);
  k_conv3m<128,128,256,128,2,1><<<dim3(2,128,8),256,0,stream>>>(ping,c4, wtus4, mc4, pong, 0, nullptr, flag,0, B,128,128, 4);

  // decoder 3
  k_tconvm<128,64,2><<<dim3(2,128,4),256,0,stream>>>(pong, wtt3, ping, B,128,128, 2);
  n = (long long)B*256*256;
  k_mask_comb<<<grid1d(n,BK),BK,0,stream>>>(mc4, m2, mc3, B,256,256);
  k_conv3m<64,64,128,64,2,1><<<dim3(4,256,4),256,0,stream>>>(ping,c3, wtus3, mc3, pong, 0, nullptr, flag,0, B,256,256, 2);

  // decoder 2
  k_tconvm<64,32,2><<<dim3(4,256,2),256,0,stream>>>(pong, wtt2, ping, B,256,256, 1);
  n = (long long)B*512*512;
  k_mask_comb<<<grid1d(n,BK),BK,0,stream>>>(mc3, m1, mc2, B,512,512);
  k_conv3m<32,32,64,32,2,2><<<dim3(8,256,2),256,0,stream>>>(ping,c2b, wtus2, mc2, pong, 0, nullptr, flag,0, B,512,512, 1);

  // decoder 1
  k_tconvm<32,16,1><<<dim3(8,512,2),256,0,stream>>>(pong, wtt1, ping, B,512,512, 1);
  n = (long long)B*1024*1024;
  k_mask_comb<<<grid1d(n,BK),BK,0,stream>>>(mc2, m0u, mc1, B,1024,1024);
  k_conv3m<16,16,32,16,1,4><<<dim3(16,256,2),256,0,stream>>>(ping,c1, wtus1, mc1, pong, 0, nullptr, flag,0, B,1024,1024, 1);

  // head
  n = (long long)B*1024*1024;
  k_head<<<grid1d(n,BK),BK,0,stream>>>(flag, pong, w_out, mc1, d_out, B,1024,1024);
}